// Round 11
// baseline (2030.999 us; speedup 1.0000x reference)
//
#include <hip/hip_runtime.h>

static constexpr int kS  = 13294;
static constexpr int kB  = 2;
static constexpr int kBS = kB * kS;     // 26588
static constexpr int kC  = 256;
static constexpr int kH  = 8;
static constexpr int kNQ = 300;
static constexpr int kFF = 1024;
static constexpr int kNL = 6;

using short8 = __attribute__((ext_vector_type(8))) short;
using f32x4  = __attribute__((ext_vector_type(4))) float;

__device__ __forceinline__ unsigned short f2b(float f) {
  unsigned u = __builtin_bit_cast(unsigned, f);
  return (unsigned short)((u + 0x7FFF + ((u >> 16) & 1)) >> 16);
}
__device__ __forceinline__ float bf2f(unsigned short u) {
  return __builtin_bit_cast(float, ((unsigned)u) << 16);
}
__device__ __forceinline__ float bflo(unsigned u) {
  return __builtin_bit_cast(float, u << 16);
}
__device__ __forceinline__ float bfhi(unsigned u) {
  return __builtin_bit_cast(float, u & 0xFFFF0000u);
}

#if defined(__has_builtin)
#if __has_builtin(__builtin_amdgcn_global_load_lds)
#define HAS_GLL 1
#endif
#endif
#ifndef HAS_GLL
#define HAS_GLL 0
#endif

#if HAS_GLL
typedef const __attribute__((address_space(1))) void* gas_t;
typedef __attribute__((address_space(3))) void* las_t;
#define GLOAD16(gp, lp) __builtin_amdgcn_global_load_lds((gas_t)(gp), (las_t)(lp), 16, 0, 0)
#endif

// LDS XOR swizzle (T2, rule #21): linear LDS dest; global SOURCE column permuted by
// granule' = granule ^ (row & mask); reads apply the same XOR. Pure involution per row.

// ---------------- bf16 MFMA GEMM (128x128 tile, XCD-chunked 1-D grid) ----------------
template<int ACT, int OBF>
__global__ __launch_bounds__(256) void gemm_mfma(
    const unsigned short* __restrict__ A, const unsigned short* __restrict__ Wt,
    const float* __restrict__ bias, void* __restrict__ outp, int M, int N, int K) {
  __shared__ __align__(16) unsigned short As[128 * 64];
  __shared__ __align__(16) unsigned short Bs[128 * 64];
  const int t = threadIdx.x;
  const int nB = N >> 7;
  const int tot = gridDim.x;
  const int q8 = tot >> 3, r8 = tot & 7;
  const int xcd = blockIdx.x & 7, pos = blockIdx.x >> 3;
  const int wg = (xcd < r8 ? xcd * (q8 + 1) : r8 * (q8 + 1) + (xcd - r8) * q8) + pos;
  const int m0 = (wg / nB) * 128, n0 = (wg % nB) * 128;
  const int wid = t >> 6, lane = t & 63;
  const int wr = wid >> 1, wc = wid & 1;
  const int srow = t >> 3;
  const int scol = (((t & 7) ^ (srow & 7)) * 8);   // swizzled source column
  const int lr = lane & 15;
  const int q4 = lane >> 4;
  const int e7 = lr & 7;

  f32x4 acc[4][4];
#pragma unroll
  for (int i = 0; i < 4; ++i)
#pragma unroll
    for (int j = 0; j < 4; ++j) acc[i][j] = (f32x4){0.f, 0.f, 0.f, 0.f};

  for (int k0 = 0; k0 < K; k0 += 64) {
#if HAS_GLL
    __syncthreads();
#pragma unroll
    for (int c = 0; c < 4; ++c) {
      int ar = m0 + c * 32 + srow; if (ar >= M) ar = M - 1;
      GLOAD16(A + (size_t)ar * K + k0 + scol, (char*)As + c * 4096 + t * 16);
      int br = n0 + c * 32 + srow; if (br >= N) br = N - 1;
      GLOAD16(Wt + (size_t)br * K + k0 + scol, (char*)Bs + c * 4096 + t * 16);
    }
    __syncthreads();
#else
    short8 ta[4], tb[4];
#pragma unroll
    for (int c = 0; c < 4; ++c) {
      int ar = m0 + c * 32 + srow; if (ar >= M) ar = M - 1;
      ta[c] = *(const short8*)(A + (size_t)ar * K + k0 + scol);
      int br = n0 + c * 32 + srow; if (br >= N) br = N - 1;
      tb[c] = *(const short8*)(Wt + (size_t)br * K + k0 + scol);
    }
    __syncthreads();
#pragma unroll
    for (int c = 0; c < 4; ++c) {
      *(short8*)&As[c * 2048 + t * 8] = ta[c];
      *(short8*)&Bs[c * 2048 + t * 8] = tb[c];
    }
    __syncthreads();
#endif
#pragma unroll
    for (int kk = 0; kk < 2; ++kk) {
      const int pg = (((kk << 2) + q4) ^ e7) * 8;
      short8 af[4], bf[4];
#pragma unroll
      for (int mi = 0; mi < 4; ++mi)
        af[mi] = *(const short8*)&As[(wr * 64 + mi * 16 + lr) * 64 + pg];
#pragma unroll
      for (int ni = 0; ni < 4; ++ni)
        bf[ni] = *(const short8*)&Bs[(wc * 64 + ni * 16 + lr) * 64 + pg];
#pragma unroll
      for (int mi = 0; mi < 4; ++mi)
#pragma unroll
        for (int ni = 0; ni < 4; ++ni)
          acc[mi][ni] = __builtin_amdgcn_mfma_f32_16x16x32_bf16(af[mi], bf[ni], acc[mi][ni], 0, 0, 0);
    }
  }
  const int orow0 = m0 + wr * 64;
  const int ocol = n0 + wc * 64 + lr;
  float bv[4];
#pragma unroll
  for (int ni = 0; ni < 4; ++ni) bv[ni] = bias[ocol + ni * 16];
#pragma unroll
  for (int mi = 0; mi < 4; ++mi) {
#pragma unroll
    for (int j = 0; j < 4; ++j) {
      const int r = orow0 + mi * 16 + q4 * 4 + j;
      if (r < M) {
#pragma unroll
        for (int ni = 0; ni < 4; ++ni) {
          float v = acc[mi][ni][j] + bv[ni];
          if (ACT) v = fmaxf(v, 0.f);
          if (OBF) ((unsigned short*)outp)[(size_t)r * N + ocol + ni * 16] = f2b(v);
          else     ((float*)outp)[(size_t)r * N + ocol + ni * 16] = v;
        }
      }
    }
  }
}

// ---------------- small-tile GEMM (64x64) ----------------
template<int ACT, int OBF>
__global__ __launch_bounds__(256) void gemm_mfma_s(
    const unsigned short* __restrict__ A, const unsigned short* __restrict__ Wt,
    const float* __restrict__ bias, void* __restrict__ outp, int M, int N, int K) {
  __shared__ __align__(16) unsigned short As[64 * 64];
  __shared__ __align__(16) unsigned short Bs[64 * 64];
  const int t = threadIdx.x;
  const int m0 = blockIdx.y * 64, n0 = blockIdx.x * 64;
  const int wid = t >> 6, lane = t & 63;
  const int wr = wid >> 1, wc = wid & 1;
  const int srow = t >> 3;
  const int scol = (((t & 7) ^ (srow & 7)) * 8);
  const int lr = lane & 15;
  const int q4 = lane >> 4;
  const int e7 = lr & 7;

  f32x4 acc[2][2];
#pragma unroll
  for (int i = 0; i < 2; ++i)
#pragma unroll
    for (int j = 0; j < 2; ++j) acc[i][j] = (f32x4){0.f, 0.f, 0.f, 0.f};

  for (int k0 = 0; k0 < K; k0 += 64) {
#if HAS_GLL
    __syncthreads();
#pragma unroll
    for (int c = 0; c < 2; ++c) {
      int ar = m0 + c * 32 + srow; if (ar >= M) ar = M - 1;
      GLOAD16(A + (size_t)ar * K + k0 + scol, (char*)As + c * 4096 + t * 16);
      int br = n0 + c * 32 + srow; if (br >= N) br = N - 1;
      GLOAD16(Wt + (size_t)br * K + k0 + scol, (char*)Bs + c * 4096 + t * 16);
    }
    __syncthreads();
#else
    short8 ta[2], tb[2];
#pragma unroll
    for (int c = 0; c < 2; ++c) {
      int ar = m0 + c * 32 + srow; if (ar >= M) ar = M - 1;
      ta[c] = *(const short8*)(A + (size_t)ar * K + k0 + scol);
      int br = n0 + c * 32 + srow; if (br >= N) br = N - 1;
      tb[c] = *(const short8*)(Wt + (size_t)br * K + k0 + scol);
    }
    __syncthreads();
#pragma unroll
    for (int c = 0; c < 2; ++c) {
      *(short8*)&As[c * 2048 + t * 8] = ta[c];
      *(short8*)&Bs[c * 2048 + t * 8] = tb[c];
    }
    __syncthreads();
#endif
#pragma unroll
    for (int kk = 0; kk < 2; ++kk) {
      const int pg = (((kk << 2) + q4) ^ e7) * 8;
      short8 af[2], bf[2];
#pragma unroll
      for (int mi = 0; mi < 2; ++mi)
        af[mi] = *(const short8*)&As[(wr * 32 + mi * 16 + lr) * 64 + pg];
#pragma unroll
      for (int ni = 0; ni < 2; ++ni)
        bf[ni] = *(const short8*)&Bs[(wc * 32 + ni * 16 + lr) * 64 + pg];
#pragma unroll
      for (int mi = 0; mi < 2; ++mi)
#pragma unroll
        for (int ni = 0; ni < 2; ++ni)
          acc[mi][ni] = __builtin_amdgcn_mfma_f32_16x16x32_bf16(af[mi], bf[ni], acc[mi][ni], 0, 0, 0);
    }
  }
  const int orow0 = m0 + wr * 32;
  const int ocol = n0 + wc * 32 + lr;
  float bv[2];
#pragma unroll
  for (int ni = 0; ni < 2; ++ni) bv[ni] = bias[ocol + ni * 16];
#pragma unroll
  for (int mi = 0; mi < 2; ++mi) {
#pragma unroll
    for (int j = 0; j < 4; ++j) {
      const int r = orow0 + mi * 16 + q4 * 4 + j;
      if (r < M) {
#pragma unroll
        for (int ni = 0; ni < 2; ++ni) {
          float v = acc[mi][ni][j] + bv[ni];
          if (ACT) v = fmaxf(v, 0.f);
          if (OBF) ((unsigned short*)outp)[(size_t)r * N + ocol + ni * 16] = f2b(v);
          else     ((float*)outp)[(size_t)r * N + ocol + ni * 16] = v;
        }
      }
    }
  }
}

// ---------------- fused GEMM + residual(bf16) + LayerNorm (BM=64, N=256, BK=128) ----------------
// 64 MFMA per barrier; weight tile reused across 64 A-rows; 16-granule XOR swizzle.
template<int WRITEQ, int WRITEF>
__global__ __launch_bounds__(256) void gemm_ln_k(
    const unsigned short* __restrict__ A, const unsigned short* __restrict__ Wt,
    const float* __restrict__ bias, const unsigned short* __restrict__ x_bf,
    const float* __restrict__ g, const float* __restrict__ be,
    float* __restrict__ outf, unsigned short* __restrict__ outb,
    unsigned short* __restrict__ qout, const unsigned short* __restrict__ poslev,
    int M, int K) {
  __shared__ __align__(16) unsigned short As[64 * 128];     // 16 KB
  __shared__ __align__(16) unsigned short Bs[256 * 128];    // 64 KB
  __shared__ float rsum[64][4], rsq[64][4], rmv[64][2];
  const int t = threadIdx.x;
  const int m0 = blockIdx.x * 64;
  const int wid = t >> 6, lane = t & 63;
  const int lr = lane & 15;
  const int q4 = lane >> 4;
  const int t16 = t >> 4;        // 0..15 (staging sub-row)
  const int g16 = (t & 15) ^ t16; // swizzled source granule

  f32x4 acc[4][4];
#pragma unroll
  for (int i = 0; i < 4; ++i)
#pragma unroll
    for (int j = 0; j < 4; ++j) acc[i][j] = (f32x4){0.f, 0.f, 0.f, 0.f};

  for (int k0 = 0; k0 < K; k0 += 128) {
#if HAS_GLL
    __syncthreads();
#pragma unroll
    for (int c = 0; c < 4; ++c) {
      int ar = m0 + c * 16 + t16; if (ar >= M) ar = M - 1;
      GLOAD16(A + (size_t)ar * K + k0 + g16 * 8, (char*)As + c * 4096 + t * 16);
    }
#pragma unroll
    for (int c = 0; c < 16; ++c) {
      const int br = c * 16 + t16;
      GLOAD16(Wt + (size_t)br * K + k0 + g16 * 8, (char*)Bs + c * 4096 + t * 16);
    }
    __syncthreads();
#else
    short8 ta[4], tb[16];
#pragma unroll
    for (int c = 0; c < 4; ++c) {
      int ar = m0 + c * 16 + t16; if (ar >= M) ar = M - 1;
      ta[c] = *(const short8*)(A + (size_t)ar * K + k0 + g16 * 8);
    }
#pragma unroll
    for (int c = 0; c < 16; ++c)
      tb[c] = *(const short8*)(Wt + (size_t)(c * 16 + t16) * K + k0 + g16 * 8);
    __syncthreads();
#pragma unroll
    for (int c = 0; c < 4; ++c) *(short8*)&As[c * 2048 + t * 8] = ta[c];
#pragma unroll
    for (int c = 0; c < 16; ++c) *(short8*)&Bs[c * 2048 + t * 8] = tb[c];
    __syncthreads();
#endif
#pragma unroll
    for (int kk = 0; kk < 4; ++kk) {
      const int pg = (((kk << 2) + q4) ^ lr) * 8;
      short8 af[4], bf[4];
#pragma unroll
      for (int mi = 0; mi < 4; ++mi)
        af[mi] = *(const short8*)&As[(mi * 16 + lr) * 128 + pg];
#pragma unroll
      for (int ni = 0; ni < 4; ++ni)
        bf[ni] = *(const short8*)&Bs[(wid * 64 + ni * 16 + lr) * 128 + pg];
#pragma unroll
      for (int mi = 0; mi < 4; ++mi)
#pragma unroll
        for (int ni = 0; ni < 4; ++ni)
          acc[mi][ni] = __builtin_amdgcn_mfma_f32_16x16x32_bf16(af[mi], bf[ni], acc[mi][ni], 0, 0, 0);
    }
  }
  float bv[4], gv[4], bev[4];
  int cols[4];
#pragma unroll
  for (int ni = 0; ni < 4; ++ni) {
    cols[ni] = wid * 64 + ni * 16 + lr;
    bv[ni] = bias[cols[ni]];
    gv[ni] = g[cols[ni]];
    bev[ni] = be[cols[ni]];
  }
#pragma unroll
  for (int mi = 0; mi < 4; ++mi) {
#pragma unroll
    for (int j = 0; j < 4; ++j) {
      const int brow = mi * 16 + q4 * 4 + j;
      int grow = m0 + brow; if (grow >= M) grow = M - 1;
      const unsigned short* xr = x_bf + (size_t)grow * 256;
      float s = 0.f, s2 = 0.f;
#pragma unroll
      for (int ni = 0; ni < 4; ++ni) {
        float v = acc[mi][ni][j] + bv[ni] + bf2f(xr[cols[ni]]);
        acc[mi][ni][j] = v;
        s += v; s2 += v * v;
      }
#pragma unroll
      for (int o = 1; o < 16; o <<= 1) {
        s += __shfl_xor(s, o);
        s2 += __shfl_xor(s2, o);
      }
      if (lr == 0) { rsum[brow][wid] = s; rsq[brow][wid] = s2; }
    }
  }
  __syncthreads();
  if (t < 64) {
    float s = rsum[t][0] + rsum[t][1] + rsum[t][2] + rsum[t][3];
    float s2 = rsq[t][0] + rsq[t][1] + rsq[t][2] + rsq[t][3];
    float mean = s * (1.f / 256.f);
    float var = s2 * (1.f / 256.f) - mean * mean;
    rmv[t][0] = mean;
    rmv[t][1] = rsqrtf(var + 1e-5f);
  }
  __syncthreads();
#pragma unroll
  for (int mi = 0; mi < 4; ++mi) {
#pragma unroll
    for (int j = 0; j < 4; ++j) {
      const int brow = mi * 16 + q4 * 4 + j;
      const int grow = m0 + brow;
      if (grow >= M) continue;
      const float mean = rmv[brow][0], rs = rmv[brow][1];
#pragma unroll
      for (int ni = 0; ni < 4; ++ni) {
        const float v = (acc[mi][ni][j] - mean) * rs * gv[ni] + bev[ni];
        const size_t oi = (size_t)grow * 256 + cols[ni];
        if (WRITEF) outf[oi] = v;
        outb[oi] = f2b(v);
        if (WRITEQ) qout[oi] = f2b(v + bf2f(poslev[oi]));
      }
    }
  }
}

// ---------------- casts / packs ----------------
__global__ void cast_bf_k(const float* __restrict__ in, unsigned short* __restrict__ out, int n4) {
  int i = blockIdx.x * 256 + threadIdx.x;
  if (i >= n4) return;
  float4 v = ((const float4*)in)[i];
  ushort4 o; o.x = f2b(v.x); o.y = f2b(v.y); o.z = f2b(v.z); o.w = f2b(v.w);
  ((ushort4*)out)[i] = o;
}

__global__ void pack_bias_k(const float* __restrict__ so_b, const float* __restrict__ aw_b,
                            float* __restrict__ fb) {
  int i = blockIdx.x * 256 + threadIdx.x;
  if (i >= kNL * 384) return;
  int l = i / 384, j = i - l * 384;
  fb[i] = (j < 256) ? so_b[l * 256 + j] : aw_b[l * 128 + j - 256];
}

// ---------------- poslev = bf16(pos + level_embed) ----------------
__global__ void poslev_k(const float* __restrict__ pos, const float* __restrict__ lev,
                         unsigned short* __restrict__ out, int n4) {
  int i = blockIdx.x * 256 + threadIdx.x;
  if (i >= n4) return;
  int c4 = i & 63;
  int row = i >> 6;
  int s = row % kS;
  int l = (s < 10000) ? 0 : (s < 12500) ? 1 : (s < 13125) ? 2 : 3;
  float4 p = ((const float4*)pos)[i];
  float4 lv = ((const float4*)(lev + l * kC))[c4];
  ushort4 o;
  o.x = f2b(p.x + lv.x); o.y = f2b(p.y + lv.y);
  o.z = f2b(p.z + lv.z); o.w = f2b(p.w + lv.w);
  ((ushort4*)out)[i] = o;
}

// ---------------- initial q = bf16(src + poslev) ----------------
__global__ void enc_q_k(const float* __restrict__ src, const unsigned short* __restrict__ poslev,
                        unsigned short* __restrict__ q, int n4) {
  int i = blockIdx.x * 256 + threadIdx.x;
  if (i >= n4) return;
  float4 m = ((const float4*)src)[i];
  ushort4 pl = ((const ushort4*)poslev)[i];
  ushort4 o;
  o.x = f2b(m.x + bf2f(pl.x)); o.y = f2b(m.y + bf2f(pl.y));
  o.z = f2b(m.z + bf2f(pl.z)); o.w = f2b(m.w + bf2f(pl.w));
  ((ushort4*)q)[i] = o;
}

// ---------------- encoder reference points ----------------
__global__ void refs_k(float* __restrict__ refS) {
  int s = blockIdx.x * 256 + threadIdx.x;
  if (s >= kS) return;
  int st, W;
  if (s < 10000)      { st = 0;     W = 100; }
  else if (s < 12500) { st = 10000; W = 50; }
  else if (s < 13125) { st = 12500; W = 25; }
  else                { st = 13125; W = 13; }
  int idx = s - st;
  int y = idx / W;
  int x = idx - y * W;
  refS[s * 2 + 0] = (x + 0.5f) / (float)W;
  refS[s * 2 + 1] = (y + 0.5f) / (float)W;
}

// ---------------- fused MSDA: 2 queries/block, saddr gathers, bf16 foab ----------------
__global__ __launch_bounds__(256) void msda_fused_k(
    const unsigned short* __restrict__ value, int vstride, int vcol,
    const unsigned short* __restrict__ foab, const float* __restrict__ refs,
    unsigned short* __restrict__ out, int Mq) {
  __shared__ int   sidx[16][2][kH][4];
  __shared__ float sw[16][2][kH][4];
  const int t = threadIdx.x;
  const int bq0 = blockIdx.x * 2;
  const int qq = t >> 7;
  {
    const int bq = bq0 + qq;
    const int b = (bq >= Mq) ? 1 : 0;
    const int qi = bq - b * Mq;
    const int h = (t >> 4) & 7, lp = t & 15, l = lp >> 2;
    const unsigned short* row = foab + (size_t)bq * 384;
    float logit = bf2f(row[256 + h * 16 + lp]);
    float mx = logit;
#pragma unroll
    for (int o = 1; o < 16; o <<= 1) mx = fmaxf(mx, __shfl_xor(mx, o));
    float e = __expf(logit - mx), ssum = e;
#pragma unroll
    for (int o = 1; o < 16; o <<= 1) ssum += __shfl_xor(ssum, o);
    const float a = e / ssum;
    const unsigned opair = *(const unsigned*)(row + h * 32 + lp * 2);
    const float offx = bflo(opair);
    const float offy = bfhi(opair);
    const float rx = refs[qi * 2 + 0];
    const float ry = refs[qi * 2 + 1];
    const int wtab[4] = {100, 50, 25, 13};
    const int stab[4] = {0, 10000, 12500, 13125};
    const int W = wtab[l];
    const int start = stab[l];
    const float px = fmaf(rx, (float)W, offx) - 0.5f;
    const float py = fmaf(ry, (float)W, offy) - 0.5f;
    const float fx = floorf(px), fy = floorf(py);
    const float wx = px - fx, wy = py - fy;
    const int x0 = (int)fx, y0 = (int)fy;
    const int x0c = min(max(x0, 0), W - 1);
    const int x1c = min(max(x0 + 1, 0), W - 1);
    const int y0c = min(max(y0, 0), W - 1);
    const int y1c = min(max(y0 + 1, 0), W - 1);
    const float vx0 = (x0 >= 0 && x0 < W) ? 1.f : 0.f;
    const float vx1 = (x0 + 1 >= 0 && x0 + 1 < W) ? 1.f : 0.f;
    const float vy0 = (y0 >= 0 && y0 < W) ? 1.f : 0.f;
    const float vy1 = (y0 + 1 >= 0 && y0 + 1 < W) ? 1.f : 0.f;
    const int base0 = b * kS * vstride + vcol + start * vstride;
    sidx[lp][qq][h][0] = base0 + (y0c * W + x0c) * vstride;
    sidx[lp][qq][h][1] = base0 + (y0c * W + x1c) * vstride;
    sidx[lp][qq][h][2] = base0 + (y1c * W + x0c) * vstride;
    sidx[lp][qq][h][3] = base0 + (y1c * W + x1c) * vstride;
    const float omwx = 1.f - wx, omwy = 1.f - wy;
    sw[lp][qq][h][0] = a * omwy * omwx * vy0 * vx0;
    sw[lp][qq][h][1] = a * omwy * wx * vy0 * vx1;
    sw[lp][qq][h][2] = a * wy * omwx * vy1 * vx0;
    sw[lp][qq][h][3] = a * wy * wx * vy1 * vx1;
  }
  __syncthreads();
  const int h = (t >> 4) & 7, dp = t & 15;
  const int bq = bq0 + qq;
  const int chan = h * 64 + dp * 4;
  const char* valc = (const char*)value;
  float aLo0 = 0.f, aLo1 = 0.f, aHi0 = 0.f, aHi1 = 0.f;
#pragma unroll
  for (int p0 = 0; p0 < 16; p0 += 8) {
    unsigned u[32];
    float w[32];
#pragma unroll
    for (int pp = 0; pp < 8; ++pp) {
      const int4 I = *(const int4*)&sidx[p0 + pp][qq][h][0];
      const float4 Wv = *(const float4*)&sw[p0 + pp][qq][h][0];
      u[pp * 4 + 0] = *(const unsigned*)(valc + (unsigned)(I.x + chan));
      u[pp * 4 + 1] = *(const unsigned*)(valc + (unsigned)(I.y + chan));
      u[pp * 4 + 2] = *(const unsigned*)(valc + (unsigned)(I.z + chan));
      u[pp * 4 + 3] = *(const unsigned*)(valc + (unsigned)(I.w + chan));
      w[pp * 4 + 0] = Wv.x; w[pp * 4 + 1] = Wv.y;
      w[pp * 4 + 2] = Wv.z; w[pp * 4 + 3] = Wv.w;
    }
#pragma unroll
    for (int j = 0; j < 32; j += 2) {
      aLo0 = fmaf(w[j], bflo(u[j]), aLo0);
      aHi0 = fmaf(w[j], bfhi(u[j]), aHi0);
      aLo1 = fmaf(w[j + 1], bflo(u[j + 1]), aLo1);
      aHi1 = fmaf(w[j + 1], bfhi(u[j + 1]), aHi1);
    }
  }
  const float accLo = aLo0 + aLo1;
  const float accHi = aHi0 + aHi1;
  const unsigned packed = (unsigned)f2b(accLo) | ((unsigned)f2b(accHi) << 16);
  ((unsigned*)out)[(size_t)bq * 128 + h * 16 + dp] = packed;
}

// ---------------- out_bf = bf16(a + b[i % nb]) ----------------
__global__ void add_bcast_bf_k(const float* __restrict__ a, const float* __restrict__ b,
                               unsigned short* __restrict__ out, int n4, int nb4) {
  int i = blockIdx.x * 256 + threadIdx.x;
  if (i >= n4) return;
  const float4 av = ((const float4*)a)[i];
  const float4 bv = ((const float4*)b)[i % nb4];
  ushort4 o;
  o.x = f2b(av.x + bv.x); o.y = f2b(av.y + bv.y);
  o.z = f2b(av.z + bv.z); o.w = f2b(av.w + bv.w);
  ((ushort4*)out)[i] = o;
}

// ---------------- decoder init ----------------
__global__ void dec_init_k(const float* __restrict__ qe, float* __restrict__ tgt,
                           unsigned short* __restrict__ tgt_bf, float* __restrict__ qposb) {
  int i = blockIdx.x * 256 + threadIdx.x;
  if (i >= kNQ * kC) return;
  int q = i >> 8, c = i & 255;
  qposb[i] = qe[q * 512 + c];
  float tg = qe[q * 512 + 256 + c];
  tgt[i] = tg;
  tgt[kNQ * kC + i] = tg;
  unsigned short tb = f2b(tg);
  tgt_bf[i] = tb;
  tgt_bf[kNQ * kC + i] = tb;
}

// ---------------- ref300 ----------------
__global__ __launch_bounds__(64) void ref_k(const float* __restrict__ qposb,
                                            const float* __restrict__ rw,
                                            const float* __restrict__ rb,
                                            float* __restrict__ ref300) {
  const int q = blockIdx.x;
  const int lane = threadIdx.x;
  const float4 qv = ((const float4*)(qposb + q * 256))[lane];
  const float4 w0 = ((const float4*)rw)[lane];
  const float4 w1 = ((const float4*)(rw + 256))[lane];
  float a0 = qv.x * w0.x + qv.y * w0.y + qv.z * w0.z + qv.w * w0.w;
  float a1 = qv.x * w1.x + qv.y * w1.y + qv.z * w1.z + qv.w * w1.w;
#pragma unroll
  for (int off = 32; off; off >>= 1) {
    a0 += __shfl_xor(a0, off);
    a1 += __shfl_xor(a1, off);
  }
  if (lane == 0) {
    ref300[q * 2 + 0] = 1.f / (1.f + __expf(-(a0 + rb[0])));
    ref300[q * 2 + 1] = 1.f / (1.f + __expf(-(a1 + rb[1])));
  }
}

// ---------------- decoder self-attention ----------------
__global__ __launch_bounds__(64) void dec_attn_k(const float* __restrict__ qk,
                                                 const float* __restrict__ v,
                                                 unsigned short* __restrict__ outp) {
  const int bid = blockIdx.x;
  const int q = bid % kNQ;
  const int bh = bid / kNQ;
  const int h = bh & 7;
  const int b = bh >> 3;
  const int lane = threadIdx.x;
  __shared__ float p[304];
  const float* qv = qk + ((size_t)(b * kNQ + q)) * 512 + h * 32;
  float qreg[32];
#pragma unroll
  for (int m = 0; m < 32; ++m) qreg[m] = qv[m];
  float scores[5];
  float mx = -1e30f;
#pragma unroll
  for (int j = 0; j < 5; ++j) {
    const int k = lane + j * 64;
    float sc = -1e30f;
    if (k < kNQ) {
      const float* kv = qk + ((size_t)(b * kNQ + k)) * 512 + 256 + h * 32;
      float acc = 0.f;
#pragma unroll
      for (int m = 0; m < 32; ++m) acc = fmaf(qreg[m], kv[m], acc);
      sc = acc * 0.17677669529663687f;
    }
    scores[j] = sc;
    mx = fmaxf(mx, sc);
  }
#pragma unroll
  for (int off = 32; off; off >>= 1) mx = fmaxf(mx, __shfl_xor(mx, off));
  float sum = 0.f;
#pragma unroll
  for (int j = 0; j < 5; ++j) {
    const int k = lane + j * 64;
    float e = 0.f;
    if (k < kNQ) e = __expf(scores[j] - mx);
    scores[j] = e;
    sum += e;
  }
#pragma unroll
  for (int off = 32; off; off >>= 1) sum += __shfl_xor(sum, off);
  const float inv = 1.f / sum;
#pragma unroll
  for (int j = 0; j < 5; ++j) {
    const int k = lane + j * 64;
    if (k < kNQ) p[k] = scores[j] * inv;
  }
  __syncthreads();
  const int d = lane & 31, half = lane >> 5;
  float acc = 0.f;
  for (int k = half * 150; k < half * 150 + 150; ++k)
    acc = fmaf(p[k], v[((size_t)(b * kNQ + k)) * 256 + h * 32 + d], acc);
  acc += __shfl_down(acc, 32);
  if (lane < 32) outp[((size_t)(b * kNQ + q)) * 256 + h * 32 + d] = f2b(acc);
}

// ---------------- write init_ref / ref outputs ----------------
__global__ void write_refs_k(const float* __restrict__ ref300, float* __restrict__ outp) {
  int i = blockIdx.x * 256 + threadIdx.x;
  if (i >= 1200) return;
  float v = ref300[i % 600];
  outp[153600 + i] = v;
  outp[154800 + i] = v;
}

__global__ void sentinel_k(float* __restrict__ outp) {
  if (threadIdx.x < 64) outp[threadIdx.x] = 12345.0f;
}

extern "C" void kernel_launch(void* const* d_in, const int* in_sizes, int n_in,
                              void* d_out, int out_size, void* d_ws, size_t ws_size,
                              hipStream_t stream) {
  const float* src      = (const float*)d_in[0];
  const float* pos      = (const float*)d_in[1];
  const float* qe       = (const float*)d_in[2];
  const float* lev      = (const float*)d_in[3];
  const float* refp_w   = (const float*)d_in[4];
  const float* refp_b   = (const float*)d_in[5];
  const float* eso_w    = (const float*)d_in[6];
  const float* eso_b    = (const float*)d_in[7];
  const float* eaw_w    = (const float*)d_in[8];
  const float* eaw_b    = (const float*)d_in[9];
  const float* evp_w    = (const float*)d_in[10];
  const float* evp_b    = (const float*)d_in[11];
  const float* eop_w    = (const float*)d_in[12];
  const float* eop_b    = (const float*)d_in[13];
  const float* en1_g    = (const float*)d_in[14];
  const float* en1_b    = (const float*)d_in[15];
  const float* el1_w    = (const float*)d_in[16];
  const float* el1_b    = (const float*)d_in[17];
  const float* el2_w    = (const float*)d_in[18];
  const float* el2_b    = (const float*)d_in[19];
  const float* en2_g    = (const float*)d_in[20];
  const float* en2_b    = (const float*)d_in[21];
  const float* dso_w    = (const float*)d_in[22];
  const float* dso_b    = (const float*)d_in[23];
  const float* daw_w    = (const float*)d_in[24];
  const float* daw_b    = (const float*)d_in[25];
  const float* dvp_w    = (const float*)d_in[26];
  const float* dvp_b    = (const float*)d_in[27];
  const float* dop_w    = (const float*)d_in[28];
  const float* dop_b    = (const float*)d_in[29];
  const float* dsa_in_w = (const float*)d_in[30];
  const float* dsa_in_b = (const float*)d_in[31];
  const float* dsa_out_w= (const float*)d_in[32];
  const float* dsa_out_b= (const float*)d_in[33];
  const float* dn1_g    = (const float*)d_in[34];
  const float* dn1_b    = (const float*)d_in[35];
  const float* dn2_g    = (const float*)d_in[36];
  const float* dn2_b    = (const float*)d_in[37];
  const float* dn3_g    = (const float*)d_in[38];
  const float* dn3_b    = (const float*)d_in[39];
  const float* dl1_w    = (const float*)d_in[40];
  const float* dl1_b    = (const float*)d_in[41];
  const float* dl2_w    = (const float*)d_in[42];
  const float* dl2_b    = (const float*)d_in[43];

  float* Wsp = (float*)d_ws;
  size_t off = 0;
  auto alloc = [&](size_t n) { float* p = Wsp + off; off += n; return p; };
  const size_t NBC = (size_t)kBS * kC;           // 6,806,528
  unsigned short* memory_bf = (unsigned short*)alloc(NBC / 2);
  unsigned short* poslev_bf = (unsigned short*)alloc(NBC / 2);
  float* r2       = alloc(NBC);
  unsigned short* val_bf = (unsigned short*)r2;
  float* r3       = alloc(NBC / 2);
  unsigned short* qbuf_bf = (unsigned short*)r3;
  unsigned short* sampbuf_bf = (unsigned short*)r3;
  float* r4       = alloc(NBC * 2);
  unsigned short* foab_bf = (unsigned short*)r4;
  unsigned short* hid_bf = (unsigned short*)r4;
  unsigned short* val_all = (unsigned short*)r2;   // decoder overlay [kBS,1536]
  float* refS     = alloc((size_t)kS * 2 + 2);
  auto allocb = [&](size_t elems) { return (unsigned short*)alloc(elems / 2); };
  unsigned short* fesoawW = allocb((size_t)kNL * 384 * 256);
  unsigned short* evpW  = allocb((size_t)kNL * 65536);
  unsigned short* eopW  = allocb((size_t)kNL * 65536);
  unsigned short* el1W  = allocb((size_t)kNL * 262144);
  unsigned short* el2W  = allocb((size_t)kNL * 262144);
  unsigned short* fdsoawW = allocb((size_t)kNL * 384 * 256);
  unsigned short* dvpW  = allocb((size_t)kNL * 65536);
  unsigned short* dopW  = allocb((size_t)kNL * 65536);
  unsigned short* dsaiW = allocb((size_t)kNL * 196608);
  unsigned short* dsaoW = allocb((size_t)kNL * 65536);
  unsigned short* dl1W  = allocb((size_t)kNL * 262144);
  unsigned short* dl2W  = allocb((size_t)kNL * 262144);
  float* fbias_e  = alloc((size_t)kNL * 384);
  float* fbias_d  = alloc((size_t)kNL * 384);
  const size_t NQC = (size_t)kB * kNQ * kC;       // 153,600
  float* tgt      = alloc(NQC);
  unsigned short* tgt_bf = (unsigned short*)alloc(NQC / 2);
  float* qposb    = alloc((size_t)kNQ * kC);
  unsigned short* dq_bf = (unsigned short*)alloc(NQC / 2);
  float* qkbuf    = alloc(NQC * 2);
  float* vbuf     = alloc(NQC);
  unsigned short* sabuf_bf = (unsigned short*)alloc(NQC / 2);
  unsigned short* dfoab_bf = (unsigned short*)alloc((size_t)kB * kNQ * 384 / 2);
  unsigned short* dsamp_bf = (unsigned short*)alloc(NQC / 2);
  unsigned short* dffnh_bf = (unsigned short*)alloc((size_t)kB * kNQ * kFF / 2);
  float* ref300   = alloc(600);

  if (ws_size < off * sizeof(float)) {
    hipLaunchKernelGGL(sentinel_k, dim3(1), dim3(64), 0, stream, (float*)d_out);
    return;
  }

  auto GEMM = [&](const unsigned short* A, const unsigned short* Wt, const float* bias,
                  void* out, int M, int N, int K, int variant) {
    dim3 g((N / 128) * ((M + 127) / 128));
    if (variant == 1)
      hipLaunchKernelGGL((gemm_mfma<1, 1>), g, dim3(256), 0, stream, A, Wt, bias, out, M, N, K);
    else if (variant == 2)
      hipLaunchKernelGGL((gemm_mfma<0, 1>), g, dim3(256), 0, stream, A, Wt, bias, out, M, N, K);
    else
      hipLaunchKernelGGL((gemm_mfma<0, 0>), g, dim3(256), 0, stream, A, Wt, bias, out, M, N, K);
  };
  auto GEMMS = [&](const unsigned short* A, const unsigned short* Wt, const float* bias,
                   void* out, int M, int N, int K, int variant) {
    dim3 g(N / 64, (M + 63) / 64);
    if (variant == 1)
      hipLaunchKernelGGL((gemm_mfma_s<1, 1>), g, dim3(256), 0, stream, A, Wt, bias, out, M, N, K);
    else if (variant == 2)
      hipLaunchKernelGGL((gemm_mfma_s<0, 1>), g, dim3(256), 0, stream, A, Wt, bias, out, M, N, K);
    else
      hipLaunchKernelGGL((gemm_mfma_s<0, 0>), g, dim3(256), 0, stream, A, Wt, bias, out, M, N, K);
  };
  auto CASTW = [&](const float* srcw, unsigned short* dstw, size_t elems) {
    int n4 = (int)(elems / 4);
    hipLaunchKernelGGL(cast_bf_k, dim3((n4 + 255) / 256), dim3(256), 0, stream, srcw, dstw, n4);
  };

  // ---- setup ----
  for (int i = 0; i < kNL; ++i) {
    CASTW(eso_w + (size_t)i * 65536, fesoawW + (size_t)i * 98304, 65536);
    CASTW(eaw_w + (size_t)i * 32768, fesoawW + (size_t)i * 98304 + 65536, 32768);
    CASTW(dso_w + (size_t)i * 65536, fdsoawW + (size_t)i * 98304, 65536);
    CASTW(daw_w + (size_t)i * 32768, fdsoawW + (size_t)i * 98304 + 65536, 32768);
  }
  CASTW(evp_w, evpW, (size_t)kNL * 65536);
  CASTW(eop_w, eopW, (size_t)kNL * 65536);
  CASTW(el1_w, el1W, (size_t)kNL * 262144);
  CASTW(el2_w, el2W, (size_t)kNL * 262144);
  CASTW(dvp_w, dvpW, (size_t)kNL * 65536);
  CASTW(dop_w, dopW, (size_t)kNL * 65536);
  CASTW(dsa_in_w, dsaiW, (size_t)kNL * 196608);
  CASTW(dsa_out_w, dsaoW, (size_t)kNL * 65536);
  CASTW(dl1_w, dl1W, (size_t)kNL * 262144);
  CASTW(dl2_w, dl2W, (size_t)kNL * 262144);
  hipLaunchKernelGGL(pack_bias_k, dim3((kNL * 384 + 255) / 256), dim3(256), 0, stream,
                     eso_b, eaw_b, fbias_e);
  hipLaunchKernelGGL(pack_bias_k, dim3((kNL * 384 + 255) / 256), dim3(256), 0, stream,
                     dso_b, daw_b, fbias_d);
  const int n4full = kBS * 64;
  hipLaunchKernelGGL(cast_bf_k, dim3((n4full + 255) / 256), dim3(256), 0, stream,
                     src, memory_bf, n4full);
  hipLaunchKernelGGL(poslev_k, dim3((n4full + 255) / 256), dim3(256), 0, stream,
                     pos, lev, poslev_bf, n4full);
  hipLaunchKernelGGL(refs_k, dim3((kS + 255) / 256), dim3(256), 0, stream, refS);
  hipLaunchKernelGGL(enc_q_k, dim3((n4full + 255) / 256), dim3(256), 0, stream,
                     src, poslev_bf, qbuf_bf, n4full);

  const int grid_ln = (kBS + 63) / 64;   // 416
  // ---- encoder ----
  for (int i = 0; i < kNL; ++i) {
    GEMM(memory_bf, evpW + (size_t)i * 65536, evp_b + i * kC, val_bf, kBS, 256, 256, 2);
    GEMM(qbuf_bf, fesoawW + (size_t)i * 98304, fbias_e + i * 384, foab_bf, kBS, 384, 256, 2);
    hipLaunchKernelGGL(msda_fused_k, dim3(kBS / 2), dim3(256), 0, stream,
                       val_bf, 512, 0, foab_bf, refS, sampbuf_bf, kS);
    hipLaunchKernelGGL((gemm_ln_k<0, 0>), dim3(grid_ln), dim3(256), 0, stream,
                       sampbuf_bf, eopW + (size_t)i * 65536, eop_b + i * kC,
                       memory_bf, en1_g + i * kC, en1_b + i * kC,
                       (float*)nullptr, memory_bf, (unsigned short*)nullptr,
                       (const unsigned short*)nullptr, kBS, 256);
    GEMM(memory_bf, el1W + (size_t)i * 262144, el1_b + i * kFF, hid_bf, kBS, 1024, 256, 1);
    hipLaunchKernelGGL((gemm_ln_k<1, 0>), dim3(grid_ln), dim3(256), 0, stream,
                       hid_bf, el2W + (size_t)i * 262144, el2_b + i * kC,
                       memory_bf, en2_g + i * kC, en2_b + i * kC,
                       (float*)nullptr, memory_bf, qbuf_bf, poslev_bf, kBS, 1024);
  }

  // ---- decoder init ----
  hipLaunchKernelGGL(dec_init_k, dim3(300), dim3(256), 0, stream, qe, tgt, tgt_bf, qposb);
  hipLaunchKernelGGL(ref_k, dim3(kNQ), dim3(64), 0, stream, qposb, refp_w, refp_b, ref300);
  GEMM(memory_bf, dvpW, dvp_b, val_all, kBS, kNL * 256, 256, 2);

  const int dn4 = kB * kNQ * 64;
  const int qn4 = kNQ * 64;
  const int MD = kB * kNQ;
  const int grid_lnd = (MD + 63) / 64;   // 10
  // ---- decoder ----
  for (int i = 0; i < kNL; ++i) {
    hipLaunchKernelGGL(add_bcast_bf_k, dim3((dn4 + 255) / 256), dim3(256), 0, stream,
                       tgt, qposb, dq_bf, dn4, qn4);
    GEMMS(dq_bf, dsaiW + (size_t)i * 196608, dsa_in_b + i * 768, qkbuf, MD, 512, 256, 0);
    GEMMS(tgt_bf, dsaiW + (size_t)i * 196608 + (size_t)512 * 256,
          dsa_in_b + i * 768 + 512, vbuf, MD, 256, 256, 0);
    hipLaunchKernelGGL(dec_attn_k, dim3(kB * kH * kNQ), dim3(64), 0, stream,
                       qkbuf, vbuf, sabuf_bf);
    hipLaunchKernelGGL((gemm_ln_k<0, 1>), dim3(grid_lnd), dim3(256), 0, stream,
                       sabuf_bf, dsaoW + (size_t)i * 65536, dsa_out_b + i * kC,
                       tgt_bf, dn2_g + i * kC, dn2_b + i * kC,
                       tgt, tgt_bf, (unsigned short*)nullptr,
                       (const unsigned short*)nullptr, MD, 256);
    hipLaunchKernelGGL(add_bcast_bf_k, dim3((dn4 + 255) / 256), dim3(256), 0, stream,
                       tgt, qposb, dq_bf, dn4, qn4);
    GEMMS(dq_bf, fdsoawW + (size_t)i * 98304, fbias_d + i * 384, dfoab_bf, MD, 384, 256, 2);
    hipLaunchKernelGGL(msda_fused_k, dim3(MD / 2), dim3(256), 0, stream,
                       val_all, kNL * 512, i * 512, dfoab_bf, ref300, dsamp_bf, kNQ);
    hipLaunchKernelGGL((gemm_ln_k<0, 1>), dim3(grid_lnd), dim3(256), 0, stream,
                       dsamp_bf, dopW + (size_t)i * 65536, dop_b + i * kC,
                       tgt_bf, dn1_g + i * kC, dn1_b + i * kC,
                       tgt, tgt_bf, (unsigned short*)nullptr,
                       (const unsigned short*)nullptr, MD, 256);
    GEMMS(tgt_bf, dl1W + (size_t)i * 262144, dl1_b + i * kFF, dffnh_bf, MD, 1024, 256, 1);
    hipLaunchKernelGGL((gemm_ln_k<0, 1>), dim3(grid_lnd), dim3(256), 0, stream,
                       dffnh_bf, dl2W + (size_t)i * 262144, dl2_b + i * kC,
                       tgt_bf, dn3_g + i * kC, dn3_b + i * kC,
                       tgt, tgt_bf, (unsigned short*)nullptr,
                       (const unsigned short*)nullptr, MD, 1024);
  }

  hipMemcpyAsync(d_out, tgt, NQC * sizeof(float), hipMemcpyDeviceToDevice, stream);
  hipLaunchKernelGGL(write_refs_k, dim3(5), dim3(256), 0, stream, ref300, (float*)d_out);
}

// Round 12
// 1746.404 us; speedup vs baseline: 1.1630x; 1.1630x over previous
//
#include <hip/hip_runtime.h>

static constexpr int kS  = 13294;
static constexpr int kB  = 2;
static constexpr int kBS = kB * kS;     // 26588
static constexpr int kC  = 256;
static constexpr int kH  = 8;
static constexpr int kNQ = 300;
static constexpr int kFF = 1024;
static constexpr int kNL = 6;

using short8 = __attribute__((ext_vector_type(8))) short;
using f32x4  = __attribute__((ext_vector_type(4))) float;

__device__ __forceinline__ unsigned short f2b(float f) {
  unsigned u = __builtin_bit_cast(unsigned, f);
  return (unsigned short)((u + 0x7FFF + ((u >> 16) & 1)) >> 16);
}
__device__ __forceinline__ float bf2f(unsigned short u) {
  return __builtin_bit_cast(float, ((unsigned)u) << 16);
}
__device__ __forceinline__ float bflo(unsigned u) {
  return __builtin_bit_cast(float, u << 16);
}
__device__ __forceinline__ float bfhi(unsigned u) {
  return __builtin_bit_cast(float, u & 0xFFFF0000u);
}

#if defined(__has_builtin)
#if __has_builtin(__builtin_amdgcn_global_load_lds)
#define HAS_GLL 1
#endif
#endif
#ifndef HAS_GLL
#define HAS_GLL 0
#endif

#if HAS_GLL
typedef const __attribute__((address_space(1))) void* gas_t;
typedef __attribute__((address_space(3))) void* las_t;
#define GLOAD16(gp, lp) __builtin_amdgcn_global_load_lds((gas_t)(gp), (las_t)(lp), 16, 0, 0)
#endif

// LDS XOR swizzle (T2, rule #21): linear LDS dest; global SOURCE column permuted by
// granule' = granule ^ (row & mask); reads apply the same XOR. Pure involution per row.

// ---------------- bf16 MFMA GEMM (128x128 tile, XCD-chunked 1-D grid) ----------------
template<int ACT, int OBF>
__global__ __launch_bounds__(256) void gemm_mfma(
    const unsigned short* __restrict__ A, const unsigned short* __restrict__ Wt,
    const float* __restrict__ bias, void* __restrict__ outp, int M, int N, int K) {
  __shared__ __align__(16) unsigned short As[128 * 64];
  __shared__ __align__(16) unsigned short Bs[128 * 64];
  const int t = threadIdx.x;
  const int nB = N >> 7;
  const int tot = gridDim.x;
  const int q8 = tot >> 3, r8 = tot & 7;
  const int xcd = blockIdx.x & 7, pos = blockIdx.x >> 3;
  const int wg = (xcd < r8 ? xcd * (q8 + 1) : r8 * (q8 + 1) + (xcd - r8) * q8) + pos;
  const int m0 = (wg / nB) * 128, n0 = (wg % nB) * 128;
  const int wid = t >> 6, lane = t & 63;
  const int wr = wid >> 1, wc = wid & 1;
  const int srow = t >> 3;
  const int scol = (((t & 7) ^ (srow & 7)) * 8);   // swizzled source column
  const int lr = lane & 15;
  const int q4 = lane >> 4;
  const int e7 = lr & 7;

  f32x4 acc[4][4];
#pragma unroll
  for (int i = 0; i < 4; ++i)
#pragma unroll
    for (int j = 0; j < 4; ++j) acc[i][j] = (f32x4){0.f, 0.f, 0.f, 0.f};

  for (int k0 = 0; k0 < K; k0 += 64) {
#if HAS_GLL
    __syncthreads();
#pragma unroll
    for (int c = 0; c < 4; ++c) {
      int ar = m0 + c * 32 + srow; if (ar >= M) ar = M - 1;
      GLOAD16(A + (size_t)ar * K + k0 + scol, (char*)As + c * 4096 + t * 16);
      int br = n0 + c * 32 + srow; if (br >= N) br = N - 1;
      GLOAD16(Wt + (size_t)br * K + k0 + scol, (char*)Bs + c * 4096 + t * 16);
    }
    __syncthreads();
#else
    short8 ta[4], tb[4];
#pragma unroll
    for (int c = 0; c < 4; ++c) {
      int ar = m0 + c * 32 + srow; if (ar >= M) ar = M - 1;
      ta[c] = *(const short8*)(A + (size_t)ar * K + k0 + scol);
      int br = n0 + c * 32 + srow; if (br >= N) br = N - 1;
      tb[c] = *(const short8*)(Wt + (size_t)br * K + k0 + scol);
    }
    __syncthreads();
#pragma unroll
    for (int c = 0; c < 4; ++c) {
      *(short8*)&As[c * 2048 + t * 8] = ta[c];
      *(short8*)&Bs[c * 2048 + t * 8] = tb[c];
    }
    __syncthreads();
#endif
#pragma unroll
    for (int kk = 0; kk < 2; ++kk) {
      const int pg = (((kk << 2) + q4) ^ e7) * 8;
      short8 af[4], bf[4];
#pragma unroll
      for (int mi = 0; mi < 4; ++mi)
        af[mi] = *(const short8*)&As[(wr * 64 + mi * 16 + lr) * 64 + pg];
#pragma unroll
      for (int ni = 0; ni < 4; ++ni)
        bf[ni] = *(const short8*)&Bs[(wc * 64 + ni * 16 + lr) * 64 + pg];
#pragma unroll
      for (int mi = 0; mi < 4; ++mi)
#pragma unroll
        for (int ni = 0; ni < 4; ++ni)
          acc[mi][ni] = __builtin_amdgcn_mfma_f32_16x16x32_bf16(af[mi], bf[ni], acc[mi][ni], 0, 0, 0);
    }
  }
  const int orow0 = m0 + wr * 64;
  const int ocol = n0 + wc * 64 + lr;
  float bv[4];
#pragma unroll
  for (int ni = 0; ni < 4; ++ni) bv[ni] = bias[ocol + ni * 16];
#pragma unroll
  for (int mi = 0; mi < 4; ++mi) {
#pragma unroll
    for (int j = 0; j < 4; ++j) {
      const int r = orow0 + mi * 16 + q4 * 4 + j;
      if (r < M) {
#pragma unroll
        for (int ni = 0; ni < 4; ++ni) {
          float v = acc[mi][ni][j] + bv[ni];
          if (ACT) v = fmaxf(v, 0.f);
          if (OBF) ((unsigned short*)outp)[(size_t)r * N + ocol + ni * 16] = f2b(v);
          else     ((float*)outp)[(size_t)r * N + ocol + ni * 16] = v;
        }
      }
    }
  }
}

// ---------------- small-tile GEMM (64x64) ----------------
template<int ACT, int OBF>
__global__ __launch_bounds__(256) void gemm_mfma_s(
    const unsigned short* __restrict__ A, const unsigned short* __restrict__ Wt,
    const float* __restrict__ bias, void* __restrict__ outp, int M, int N, int K) {
  __shared__ __align__(16) unsigned short As[64 * 64];
  __shared__ __align__(16) unsigned short Bs[64 * 64];
  const int t = threadIdx.x;
  const int m0 = blockIdx.y * 64, n0 = blockIdx.x * 64;
  const int wid = t >> 6, lane = t & 63;
  const int wr = wid >> 1, wc = wid & 1;
  const int srow = t >> 3;
  const int scol = (((t & 7) ^ (srow & 7)) * 8);
  const int lr = lane & 15;
  const int q4 = lane >> 4;
  const int e7 = lr & 7;

  f32x4 acc[2][2];
#pragma unroll
  for (int i = 0; i < 2; ++i)
#pragma unroll
    for (int j = 0; j < 2; ++j) acc[i][j] = (f32x4){0.f, 0.f, 0.f, 0.f};

  for (int k0 = 0; k0 < K; k0 += 64) {
#if HAS_GLL
    __syncthreads();
#pragma unroll
    for (int c = 0; c < 2; ++c) {
      int ar = m0 + c * 32 + srow; if (ar >= M) ar = M - 1;
      GLOAD16(A + (size_t)ar * K + k0 + scol, (char*)As + c * 4096 + t * 16);
      int br = n0 + c * 32 + srow; if (br >= N) br = N - 1;
      GLOAD16(Wt + (size_t)br * K + k0 + scol, (char*)Bs + c * 4096 + t * 16);
    }
    __syncthreads();
#else
    short8 ta[2], tb[2];
#pragma unroll
    for (int c = 0; c < 2; ++c) {
      int ar = m0 + c * 32 + srow; if (ar >= M) ar = M - 1;
      ta[c] = *(const short8*)(A + (size_t)ar * K + k0 + scol);
      int br = n0 + c * 32 + srow; if (br >= N) br = N - 1;
      tb[c] = *(const short8*)(Wt + (size_t)br * K + k0 + scol);
    }
    __syncthreads();
#pragma unroll
    for (int c = 0; c < 2; ++c) {
      *(short8*)&As[c * 2048 + t * 8] = ta[c];
      *(short8*)&Bs[c * 2048 + t * 8] = tb[c];
    }
    __syncthreads();
#endif
#pragma unroll
    for (int kk = 0; kk < 2; ++kk) {
      const int pg = (((kk << 2) + q4) ^ e7) * 8;
      short8 af[2], bf[2];
#pragma unroll
      for (int mi = 0; mi < 2; ++mi)
        af[mi] = *(const short8*)&As[(wr * 32 + mi * 16 + lr) * 64 + pg];
#pragma unroll
      for (int ni = 0; ni < 2; ++ni)
        bf[ni] = *(const short8*)&Bs[(wc * 32 + ni * 16 + lr) * 64 + pg];
#pragma unroll
      for (int mi = 0; mi < 2; ++mi)
#pragma unroll
        for (int ni = 0; ni < 2; ++ni)
          acc[mi][ni] = __builtin_amdgcn_mfma_f32_16x16x32_bf16(af[mi], bf[ni], acc[mi][ni], 0, 0, 0);
    }
  }
  const int orow0 = m0 + wr * 32;
  const int ocol = n0 + wc * 32 + lr;
  float bv[2];
#pragma unroll
  for (int ni = 0; ni < 2; ++ni) bv[ni] = bias[ocol + ni * 16];
#pragma unroll
  for (int mi = 0; mi < 2; ++mi) {
#pragma unroll
    for (int j = 0; j < 4; ++j) {
      const int r = orow0 + mi * 16 + q4 * 4 + j;
      if (r < M) {
#pragma unroll
        for (int ni = 0; ni < 2; ++ni) {
          float v = acc[mi][ni][j] + bv[ni];
          if (ACT) v = fmaxf(v, 0.f);
          if (OBF) ((unsigned short*)outp)[(size_t)r * N + ocol + ni * 16] = f2b(v);
          else     ((float*)outp)[(size_t)r * N + ocol + ni * 16] = v;
        }
      }
    }
  }
}

// ---------------- fused GEMM + residual(bf16) + LayerNorm (BM=32, N=256, BK=128) ----------------
// LDS staging with 16-granule XOR swizzle; 8 barriers for K=1024, 32 MFMA/barrier. 2 blocks/CU.
template<int WRITEQ, int WRITEF>
__global__ __launch_bounds__(256) void gemm_ln_k(
    const unsigned short* __restrict__ A, const unsigned short* __restrict__ Wt,
    const float* __restrict__ bias, const unsigned short* __restrict__ x_bf,
    const float* __restrict__ g, const float* __restrict__ be,
    float* __restrict__ outf, unsigned short* __restrict__ outb,
    unsigned short* __restrict__ qout, const unsigned short* __restrict__ poslev,
    int M, int K) {
  __shared__ __align__(16) unsigned short As[32 * 128];     // 8 KB
  __shared__ __align__(16) unsigned short Bs[256 * 128];    // 64 KB
  __shared__ float rsum[32][4], rsq[32][4], rmv[32][2];
  const int t = threadIdx.x;
  const int m0 = blockIdx.x * 32;
  const int wid = t >> 6, lane = t & 63;
  const int lr = lane & 15;
  const int q4 = lane >> 4;
  const int t16 = t >> 4;        // 0..15 (staging sub-row)
  const int g16 = (t & 15) ^ t16; // swizzled source granule

  f32x4 acc[2][4];
#pragma unroll
  for (int i = 0; i < 2; ++i)
#pragma unroll
    for (int j = 0; j < 4; ++j) acc[i][j] = (f32x4){0.f, 0.f, 0.f, 0.f};

  for (int k0 = 0; k0 < K; k0 += 128) {
#if HAS_GLL
    __syncthreads();
#pragma unroll
    for (int c = 0; c < 2; ++c) {
      int ar = m0 + c * 16 + t16; if (ar >= M) ar = M - 1;
      GLOAD16(A + (size_t)ar * K + k0 + g16 * 8, (char*)As + c * 4096 + t * 16);
    }
#pragma unroll
    for (int c = 0; c < 16; ++c) {
      const int br = c * 16 + t16;
      GLOAD16(Wt + (size_t)br * K + k0 + g16 * 8, (char*)Bs + c * 4096 + t * 16);
    }
    __syncthreads();
#else
    short8 ta[2], tb[16];
#pragma unroll
    for (int c = 0; c < 2; ++c) {
      int ar = m0 + c * 16 + t16; if (ar >= M) ar = M - 1;
      ta[c] = *(const short8*)(A + (size_t)ar * K + k0 + g16 * 8);
    }
#pragma unroll
    for (int c = 0; c < 16; ++c)
      tb[c] = *(const short8*)(Wt + (size_t)(c * 16 + t16) * K + k0 + g16 * 8);
    __syncthreads();
#pragma unroll
    for (int c = 0; c < 2; ++c) *(short8*)&As[c * 2048 + t * 8] = ta[c];
#pragma unroll
    for (int c = 0; c < 16; ++c) *(short8*)&Bs[c * 2048 + t * 8] = tb[c];
    __syncthreads();
#endif
#pragma unroll
    for (int kk = 0; kk < 4; ++kk) {
      const int pg = (((kk << 2) + q4) ^ lr) * 8;
      short8 af[2], bf[4];
#pragma unroll
      for (int mi = 0; mi < 2; ++mi)
        af[mi] = *(const short8*)&As[(mi * 16 + lr) * 128 + pg];
#pragma unroll
      for (int ni = 0; ni < 4; ++ni)
        bf[ni] = *(const short8*)&Bs[(wid * 64 + ni * 16 + lr) * 128 + pg];
#pragma unroll
      for (int mi = 0; mi < 2; ++mi)
#pragma unroll
        for (int ni = 0; ni < 4; ++ni)
          acc[mi][ni] = __builtin_amdgcn_mfma_f32_16x16x32_bf16(af[mi], bf[ni], acc[mi][ni], 0, 0, 0);
    }
  }
  float bv[4], gv[4], bev[4];
  int cols[4];
#pragma unroll
  for (int ni = 0; ni < 4; ++ni) {
    cols[ni] = wid * 64 + ni * 16 + lr;
    bv[ni] = bias[cols[ni]];
    gv[ni] = g[cols[ni]];
    bev[ni] = be[cols[ni]];
  }
#pragma unroll
  for (int mi = 0; mi < 2; ++mi) {
#pragma unroll
    for (int j = 0; j < 4; ++j) {
      const int brow = mi * 16 + q4 * 4 + j;
      int grow = m0 + brow; if (grow >= M) grow = M - 1;
      const unsigned short* xr = x_bf + (size_t)grow * 256;
      float s = 0.f, s2 = 0.f;
#pragma unroll
      for (int ni = 0; ni < 4; ++ni) {
        float v = acc[mi][ni][j] + bv[ni] + bf2f(xr[cols[ni]]);
        acc[mi][ni][j] = v;
        s += v; s2 += v * v;
      }
#pragma unroll
      for (int o = 1; o < 16; o <<= 1) {
        s += __shfl_xor(s, o);
        s2 += __shfl_xor(s2, o);
      }
      if (lr == 0) { rsum[brow][wid] = s; rsq[brow][wid] = s2; }
    }
  }
  __syncthreads();
  if (t < 32) {
    float s = rsum[t][0] + rsum[t][1] + rsum[t][2] + rsum[t][3];
    float s2 = rsq[t][0] + rsq[t][1] + rsq[t][2] + rsq[t][3];
    float mean = s * (1.f / 256.f);
    float var = s2 * (1.f / 256.f) - mean * mean;
    rmv[t][0] = mean;
    rmv[t][1] = rsqrtf(var + 1e-5f);
  }
  __syncthreads();
#pragma unroll
  for (int mi = 0; mi < 2; ++mi) {
#pragma unroll
    for (int j = 0; j < 4; ++j) {
      const int brow = mi * 16 + q4 * 4 + j;
      const int grow = m0 + brow;
      if (grow >= M) continue;
      const float mean = rmv[brow][0], rs = rmv[brow][1];
#pragma unroll
      for (int ni = 0; ni < 4; ++ni) {
        const float v = (acc[mi][ni][j] - mean) * rs * gv[ni] + bev[ni];
        const size_t oi = (size_t)grow * 256 + cols[ni];
        if (WRITEF) outf[oi] = v;
        outb[oi] = f2b(v);
        if (WRITEQ) qout[oi] = f2b(v + bf2f(poslev[oi]));
      }
    }
  }
}

// ---------------- casts / packs ----------------
__global__ void cast_bf_k(const float* __restrict__ in, unsigned short* __restrict__ out, int n4) {
  int i = blockIdx.x * 256 + threadIdx.x;
  if (i >= n4) return;
  float4 v = ((const float4*)in)[i];
  ushort4 o; o.x = f2b(v.x); o.y = f2b(v.y); o.z = f2b(v.z); o.w = f2b(v.w);
  ((ushort4*)out)[i] = o;
}

__global__ void pack_bias_k(const float* __restrict__ so_b, const float* __restrict__ aw_b,
                            float* __restrict__ fb) {
  int i = blockIdx.x * 256 + threadIdx.x;
  if (i >= kNL * 384) return;
  int l = i / 384, j = i - l * 384;
  fb[i] = (j < 256) ? so_b[l * 256 + j] : aw_b[l * 128 + j - 256];
}

// ---------------- poslev = bf16(pos + level_embed) ----------------
__global__ void poslev_k(const float* __restrict__ pos, const float* __restrict__ lev,
                         unsigned short* __restrict__ out, int n4) {
  int i = blockIdx.x * 256 + threadIdx.x;
  if (i >= n4) return;
  int c4 = i & 63;
  int row = i >> 6;
  int s = row % kS;
  int l = (s < 10000) ? 0 : (s < 12500) ? 1 : (s < 13125) ? 2 : 3;
  float4 p = ((const float4*)pos)[i];
  float4 lv = ((const float4*)(lev + l * kC))[c4];
  ushort4 o;
  o.x = f2b(p.x + lv.x); o.y = f2b(p.y + lv.y);
  o.z = f2b(p.z + lv.z); o.w = f2b(p.w + lv.w);
  ((ushort4*)out)[i] = o;
}

// ---------------- initial q = bf16(src + poslev) ----------------
__global__ void enc_q_k(const float* __restrict__ src, const unsigned short* __restrict__ poslev,
                        unsigned short* __restrict__ q, int n4) {
  int i = blockIdx.x * 256 + threadIdx.x;
  if (i >= n4) return;
  float4 m = ((const float4*)src)[i];
  ushort4 pl = ((const ushort4*)poslev)[i];
  ushort4 o;
  o.x = f2b(m.x + bf2f(pl.x)); o.y = f2b(m.y + bf2f(pl.y));
  o.z = f2b(m.z + bf2f(pl.z)); o.w = f2b(m.w + bf2f(pl.w));
  ((ushort4*)q)[i] = o;
}

// ---------------- encoder reference points ----------------
__global__ void refs_k(float* __restrict__ refS) {
  int s = blockIdx.x * 256 + threadIdx.x;
  if (s >= kS) return;
  int st, W;
  if (s < 10000)      { st = 0;     W = 100; }
  else if (s < 12500) { st = 10000; W = 50; }
  else if (s < 13125) { st = 12500; W = 25; }
  else                { st = 13125; W = 13; }
  int idx = s - st;
  int y = idx / W;
  int x = idx - y * W;
  refS[s * 2 + 0] = (x + 0.5f) / (float)W;
  refS[s * 2 + 1] = (y + 0.5f) / (float)W;
}

// ---------------- fused MSDA: 2 queries/block, saddr gathers, bf16 foab ----------------
__global__ __launch_bounds__(256) void msda_fused_k(
    const unsigned short* __restrict__ value, int vstride, int vcol,
    const unsigned short* __restrict__ foab, const float* __restrict__ refs,
    unsigned short* __restrict__ out, int Mq) {
  __shared__ int   sidx[16][2][kH][4];
  __shared__ float sw[16][2][kH][4];
  const int t = threadIdx.x;
  const int bq0 = blockIdx.x * 2;
  const int qq = t >> 7;
  {
    const int bq = bq0 + qq;
    const int b = (bq >= Mq) ? 1 : 0;
    const int qi = bq - b * Mq;
    const int h = (t >> 4) & 7, lp = t & 15, l = lp >> 2;
    const unsigned short* row = foab + (size_t)bq * 384;
    float logit = bf2f(row[256 + h * 16 + lp]);
    float mx = logit;
#pragma unroll
    for (int o = 1; o < 16; o <<= 1) mx = fmaxf(mx, __shfl_xor(mx, o));
    float e = __expf(logit - mx), ssum = e;
#pragma unroll
    for (int o = 1; o < 16; o <<= 1) ssum += __shfl_xor(ssum, o);
    const float a = e / ssum;
    const unsigned opair = *(const unsigned*)(row + h * 32 + lp * 2);
    const float offx = bflo(opair);
    const float offy = bfhi(opair);
    const float rx = refs[qi * 2 + 0];
    const float ry = refs[qi * 2 + 1];
    const int wtab[4] = {100, 50, 25, 13};
    const int stab[4] = {0, 10000, 12500, 13125};
    const int W = wtab[l];
    const int start = stab[l];
    const float px = fmaf(rx, (float)W, offx) - 0.5f;
    const float py = fmaf(ry, (float)W, offy) - 0.5f;
    const float fx = floorf(px), fy = floorf(py);
    const float wx = px - fx, wy = py - fy;
    const int x0 = (int)fx, y0 = (int)fy;
    const int x0c = min(max(x0, 0), W - 1);
    const int x1c = min(max(x0 + 1, 0), W - 1);
    const int y0c = min(max(y0, 0), W - 1);
    const int y1c = min(max(y0 + 1, 0), W - 1);
    const float vx0 = (x0 >= 0 && x0 < W) ? 1.f : 0.f;
    const float vx1 = (x0 + 1 >= 0 && x0 + 1 < W) ? 1.f : 0.f;
    const float vy0 = (y0 >= 0 && y0 < W) ? 1.f : 0.f;
    const float vy1 = (y0 + 1 >= 0 && y0 + 1 < W) ? 1.f : 0.f;
    const int base0 = b * kS * vstride + vcol + start * vstride;
    sidx[lp][qq][h][0] = base0 + (y0c * W + x0c) * vstride;
    sidx[lp][qq][h][1] = base0 + (y0c * W + x1c) * vstride;
    sidx[lp][qq][h][2] = base0 + (y1c * W + x0c) * vstride;
    sidx[lp][qq][h][3] = base0 + (y1c * W + x1c) * vstride;
    const float omwx = 1.f - wx, omwy = 1.f - wy;
    sw[lp][qq][h][0] = a * omwy * omwx * vy0 * vx0;
    sw[lp][qq][h][1] = a * omwy * wx * vy0 * vx1;
    sw[lp][qq][h][2] = a * wy * omwx * vy1 * vx0;
    sw[lp][qq][h][3] = a * wy * wx * vy1 * vx1;
  }
  __syncthreads();
  const int h = (t >> 4) & 7, dp = t & 15;
  const int bq = bq0 + qq;
  const int chan = h * 64 + dp * 4;
  const char* valc = (const char*)value;
  float aLo0 = 0.f, aLo1 = 0.f, aHi0 = 0.f, aHi1 = 0.f;
#pragma unroll
  for (int p0 = 0; p0 < 16; p0 += 8) {
    unsigned u[32];
    float w[32];
#pragma unroll
    for (int pp = 0; pp < 8; ++pp) {
      const int4 I = *(const int4*)&sidx[p0 + pp][qq][h][0];
      const float4 Wv = *(const float4*)&sw[p0 + pp][qq][h][0];
      u[pp * 4 + 0] = *(const unsigned*)(valc + (unsigned)(I.x + chan));
      u[pp * 4 + 1] = *(const unsigned*)(valc + (unsigned)(I.y + chan));
      u[pp * 4 + 2] = *(const unsigned*)(valc + (unsigned)(I.z + chan));
      u[pp * 4 + 3] = *(const unsigned*)(valc + (unsigned)(I.w + chan));
      w[pp * 4 + 0] = Wv.x; w[pp * 4 + 1] = Wv.y;
      w[pp * 4 + 2] = Wv.z; w[pp * 4 + 3] = Wv.w;
    }
#pragma unroll
    for (int j = 0; j < 32; j += 2) {
      aLo0 = fmaf(w[j], bflo(u[j]), aLo0);
      aHi0 = fmaf(w[j], bfhi(u[j]), aHi0);
      aLo1 = fmaf(w[j + 1], bflo(u[j + 1]), aLo1);
      aHi1 = fmaf(w[j + 1], bfhi(u[j + 1]), aHi1);
    }
  }
  const float accLo = aLo0 + aLo1;
  const float accHi = aHi0 + aHi1;
  const unsigned packed = (unsigned)f2b(accLo) | ((unsigned)f2b(accHi) << 16);
  ((unsigned*)out)[(size_t)bq * 128 + h * 16 + dp] = packed;
}

// ---------------- out_bf = bf16(a + b[i % nb]) ----------------
__global__ void add_bcast_bf_k(const float* __restrict__ a, const float* __restrict__ b,
                               unsigned short* __restrict__ out, int n4, int nb4) {
  int i = blockIdx.x * 256 + threadIdx.x;
  if (i >= n4) return;
  const float4 av = ((const float4*)a)[i];
  const float4 bv = ((const float4*)b)[i % nb4];
  ushort4 o;
  o.x = f2b(av.x + bv.x); o.y = f2b(av.y + bv.y);
  o.z = f2b(av.z + bv.z); o.w = f2b(av.w + bv.w);
  ((ushort4*)out)[i] = o;
}

// ---------------- decoder init ----------------
__global__ void dec_init_k(const float* __restrict__ qe, float* __restrict__ tgt,
                           unsigned short* __restrict__ tgt_bf, float* __restrict__ qposb) {
  int i = blockIdx.x * 256 + threadIdx.x;
  if (i >= kNQ * kC) return;
  int q = i >> 8, c = i & 255;
  qposb[i] = qe[q * 512 + c];
  float tg = qe[q * 512 + 256 + c];
  tgt[i] = tg;
  tgt[kNQ * kC + i] = tg;
  unsigned short tb = f2b(tg);
  tgt_bf[i] = tb;
  tgt_bf[kNQ * kC + i] = tb;
}

// ---------------- ref300 ----------------
__global__ __launch_bounds__(64) void ref_k(const float* __restrict__ qposb,
                                            const float* __restrict__ rw,
                                            const float* __restrict__ rb,
                                            float* __restrict__ ref300) {
  const int q = blockIdx.x;
  const int lane = threadIdx.x;
  const float4 qv = ((const float4*)(qposb + q * 256))[lane];
  const float4 w0 = ((const float4*)rw)[lane];
  const float4 w1 = ((const float4*)(rw + 256))[lane];
  float a0 = qv.x * w0.x + qv.y * w0.y + qv.z * w0.z + qv.w * w0.w;
  float a1 = qv.x * w1.x + qv.y * w1.y + qv.z * w1.z + qv.w * w1.w;
#pragma unroll
  for (int off = 32; off; off >>= 1) {
    a0 += __shfl_xor(a0, off);
    a1 += __shfl_xor(a1, off);
  }
  if (lane == 0) {
    ref300[q * 2 + 0] = 1.f / (1.f + __expf(-(a0 + rb[0])));
    ref300[q * 2 + 1] = 1.f / (1.f + __expf(-(a1 + rb[1])));
  }
}

// ---------------- decoder self-attention ----------------
__global__ __launch_bounds__(64) void dec_attn_k(const float* __restrict__ qk,
                                                 const float* __restrict__ v,
                                                 unsigned short* __restrict__ outp) {
  const int bid = blockIdx.x;
  const int q = bid % kNQ;
  const int bh = bid / kNQ;
  const int h = bh & 7;
  const int b = bh >> 3;
  const int lane = threadIdx.x;
  __shared__ float p[304];
  const float* qv = qk + ((size_t)(b * kNQ + q)) * 512 + h * 32;
  float qreg[32];
#pragma unroll
  for (int m = 0; m < 32; ++m) qreg[m] = qv[m];
  float scores[5];
  float mx = -1e30f;
#pragma unroll
  for (int j = 0; j < 5; ++j) {
    const int k = lane + j * 64;
    float sc = -1e30f;
    if (k < kNQ) {
      const float* kv = qk + ((size_t)(b * kNQ + k)) * 512 + 256 + h * 32;
      float acc = 0.f;
#pragma unroll
      for (int m = 0; m < 32; ++m) acc = fmaf(qreg[m], kv[m], acc);
      sc = acc * 0.17677669529663687f;
    }
    scores[j] = sc;
    mx = fmaxf(mx, sc);
  }
#pragma unroll
  for (int off = 32; off; off >>= 1) mx = fmaxf(mx, __shfl_xor(mx, off));
  float sum = 0.f;
#pragma unroll
  for (int j = 0; j < 5; ++j) {
    const int k = lane + j * 64;
    float e = 0.f;
    if (k < kNQ) e = __expf(scores[j] - mx);
    scores[j] = e;
    sum += e;
  }
#pragma unroll
  for (int off = 32; off; off >>= 1) sum += __shfl_xor(sum, off);
  const float inv = 1.f / sum;
#pragma unroll
  for (int j = 0; j < 5; ++j) {
    const int k = lane + j * 64;
    if (k < kNQ) p[k] = scores[j] * inv;
  }
  __syncthreads();
  const int d = lane & 31, half = lane >> 5;
  float acc = 0.f;
  for (int k = half * 150; k < half * 150 + 150; ++k)
    acc = fmaf(p[k], v[((size_t)(b * kNQ + k)) * 256 + h * 32 + d], acc);
  acc += __shfl_down(acc, 32);
  if (lane < 32) outp[((size_t)(b * kNQ + q)) * 256 + h * 32 + d] = f2b(acc);
}

// ---------------- write init_ref / ref outputs ----------------
__global__ void write_refs_k(const float* __restrict__ ref300, float* __restrict__ outp) {
  int i = blockIdx.x * 256 + threadIdx.x;
  if (i >= 1200) return;
  float v = ref300[i % 600];
  outp[153600 + i] = v;
  outp[154800 + i] = v;
}

__global__ void sentinel_k(float* __restrict__ outp) {
  if (threadIdx.x < 64) outp[threadIdx.x] = 12345.0f;
}

extern "C" void kernel_launch(void* const* d_in, const int* in_sizes, int n_in,
                              void* d_out, int out_size, void* d_ws, size_t ws_size,
                              hipStream_t stream) {
  const float* src      = (const float*)d_in[0];
  const float* pos      = (const float*)d_in[1];
  const float* qe       = (const float*)d_in[2];
  const float* lev      = (const float*)d_in[3];
  const float* refp_w   = (const float*)d_in[4];
  const float* refp_b   = (const float*)d_in[5];
  const float* eso_w    = (const float*)d_in[6];
  const float* eso_b    = (const float*)d_in[7];
  const float* eaw_w    = (const float*)d_in[8];
  const float* eaw_b    = (const float*)d_in[9];
  const float* evp_w    = (const float*)d_in[10];
  const float* evp_b    = (const float*)d_in[11];
  const float* eop_w    = (const float*)d_in[12];
  const float* eop_b    = (const float*)d_in[13];
  const float* en1_g    = (const float*)d_in[14];
  const float* en1_b    = (const float*)d_in[15];
  const float* el1_w    = (const float*)d_in[16];
  const float* el1_b    = (const float*)d_in[17];
  const float* el2_w    = (const float*)d_in[18];
  const float* el2_b    = (const float*)d_in[19];
  const float* en2_g    = (const float*)d_in[20];
  const float* en2_b    = (const float*)d_in[21];
  const float* dso_w    = (const float*)d_in[22];
  const float* dso_b    = (const float*)d_in[23];
  const float* daw_w    = (const float*)d_in[24];
  const float* daw_b    = (const float*)d_in[25];
  const float* dvp_w    = (const float*)d_in[26];
  const float* dvp_b    = (const float*)d_in[27];
  const float* dop_w    = (const float*)d_in[28];
  const float* dop_b    = (const float*)d_in[29];
  const float* dsa_in_w = (const float*)d_in[30];
  const float* dsa_in_b = (const float*)d_in[31];
  const float* dsa_out_w= (const float*)d_in[32];
  const float* dsa_out_b= (const float*)d_in[33];
  const float* dn1_g    = (const float*)d_in[34];
  const float* dn1_b    = (const float*)d_in[35];
  const float* dn2_g    = (const float*)d_in[36];
  const float* dn2_b    = (const float*)d_in[37];
  const float* dn3_g    = (const float*)d_in[38];
  const float* dn3_b    = (const float*)d_in[39];
  const float* dl1_w    = (const float*)d_in[40];
  const float* dl1_b    = (const float*)d_in[41];
  const float* dl2_w    = (const float*)d_in[42];
  const float* dl2_b    = (const float*)d_in[43];

  float* Wsp = (float*)d_ws;
  size_t off = 0;
  auto alloc = [&](size_t n) { float* p = Wsp + off; off += n; return p; };
  const size_t NBC = (size_t)kBS * kC;           // 6,806,528
  unsigned short* memory_bf = (unsigned short*)alloc(NBC / 2);
  unsigned short* poslev_bf = (unsigned short*)alloc(NBC / 2);
  float* r2       = alloc(NBC);
  unsigned short* val_bf = (unsigned short*)r2;
  float* r3       = alloc(NBC / 2);
  unsigned short* qbuf_bf = (unsigned short*)r3;
  unsigned short* sampbuf_bf = (unsigned short*)r3;
  float* r4       = alloc(NBC * 2);
  unsigned short* foab_bf = (unsigned short*)r4;
  unsigned short* hid_bf = (unsigned short*)r4;
  unsigned short* val_all = (unsigned short*)r2;   // decoder overlay [kBS,1536]
  float* refS     = alloc((size_t)kS * 2 + 2);
  auto allocb = [&](size_t elems) { return (unsigned short*)alloc(elems / 2); };
  unsigned short* fesoawW = allocb((size_t)kNL * 384 * 256);
  unsigned short* evpW  = allocb((size_t)kNL * 65536);
  unsigned short* eopW  = allocb((size_t)kNL * 65536);
  unsigned short* el1W  = allocb((size_t)kNL * 262144);
  unsigned short* el2W  = allocb((size_t)kNL * 262144);
  unsigned short* fdsoawW = allocb((size_t)kNL * 384 * 256);
  unsigned short* dvpW  = allocb((size_t)kNL * 65536);
  unsigned short* dopW  = allocb((size_t)kNL * 65536);
  unsigned short* dsaiW = allocb((size_t)kNL * 196608);
  unsigned short* dsaoW = allocb((size_t)kNL * 65536);
  unsigned short* dl1W  = allocb((size_t)kNL * 262144);
  unsigned short* dl2W  = allocb((size_t)kNL * 262144);
  float* fbias_e  = alloc((size_t)kNL * 384);
  float* fbias_d  = alloc((size_t)kNL * 384);
  const size_t NQC = (size_t)kB * kNQ * kC;       // 153,600
  float* tgt      = alloc(NQC);
  unsigned short* tgt_bf = (unsigned short*)alloc(NQC / 2);
  float* qposb    = alloc((size_t)kNQ * kC);
  unsigned short* dq_bf = (unsigned short*)alloc(NQC / 2);
  float* qkbuf    = alloc(NQC * 2);
  float* vbuf     = alloc(NQC);
  unsigned short* sabuf_bf = (unsigned short*)alloc(NQC / 2);
  unsigned short* dfoab_bf = (unsigned short*)alloc((size_t)kB * kNQ * 384 / 2);
  unsigned short* dsamp_bf = (unsigned short*)alloc(NQC / 2);
  unsigned short* dffnh_bf = (unsigned short*)alloc((size_t)kB * kNQ * kFF / 2);
  float* ref300   = alloc(600);

  if (ws_size < off * sizeof(float)) {
    hipLaunchKernelGGL(sentinel_k, dim3(1), dim3(64), 0, stream, (float*)d_out);
    return;
  }

  auto GEMM = [&](const unsigned short* A, const unsigned short* Wt, const float* bias,
                  void* out, int M, int N, int K, int variant) {
    dim3 g((N / 128) * ((M + 127) / 128));
    if (variant == 1)
      hipLaunchKernelGGL((gemm_mfma<1, 1>), g, dim3(256), 0, stream, A, Wt, bias, out, M, N, K);
    else if (variant == 2)
      hipLaunchKernelGGL((gemm_mfma<0, 1>), g, dim3(256), 0, stream, A, Wt, bias, out, M, N, K);
    else
      hipLaunchKernelGGL((gemm_mfma<0, 0>), g, dim3(256), 0, stream, A, Wt, bias, out, M, N, K);
  };
  auto GEMMS = [&](const unsigned short* A, const unsigned short* Wt, const float* bias,
                   void* out, int M, int N, int K, int variant) {
    dim3 g(N / 64, (M + 63) / 64);
    if (variant == 1)
      hipLaunchKernelGGL((gemm_mfma_s<1, 1>), g, dim3(256), 0, stream, A, Wt, bias, out, M, N, K);
    else if (variant == 2)
      hipLaunchKernelGGL((gemm_mfma_s<0, 1>), g, dim3(256), 0, stream, A, Wt, bias, out, M, N, K);
    else
      hipLaunchKernelGGL((gemm_mfma_s<0, 0>), g, dim3(256), 0, stream, A, Wt, bias, out, M, N, K);
  };
  auto CASTW = [&](const float* srcw, unsigned short* dstw, size_t elems) {
    int n4 = (int)(elems / 4);
    hipLaunchKernelGGL(cast_bf_k, dim3((n4 + 255) / 256), dim3(256), 0, stream, srcw, dstw, n4);
  };

  // ---- setup ----
  for (int i = 0; i < kNL; ++i) {
    CASTW(eso_w + (size_t)i * 65536, fesoawW + (size_t)i * 98304, 65536);
    CASTW(eaw_w + (size_t)i * 32768, fesoawW + (size_t)i * 98304 + 65536, 32768);
    CASTW(dso_w + (size_t)i * 65536, fdsoawW + (size_t)i * 98304, 65536);
    CASTW(daw_w + (size_t)i * 32768, fdsoawW + (size_t)i * 98304 + 65536, 32768);
  }
  CASTW(evp_w, evpW, (size_t)kNL * 65536);
  CASTW(eop_w, eopW, (size_t)kNL * 65536);
  CASTW(el1_w, el1W, (size_t)kNL * 262144);
  CASTW(el2_w, el2W, (size_t)kNL * 262144);
  CASTW(dvp_w, dvpW, (size_t)kNL * 65536);
  CASTW(dop_w, dopW, (size_t)kNL * 65536);
  CASTW(dsa_in_w, dsaiW, (size_t)kNL * 196608);
  CASTW(dsa_out_w, dsaoW, (size_t)kNL * 65536);
  CASTW(dl1_w, dl1W, (size_t)kNL * 262144);
  CASTW(dl2_w, dl2W, (size_t)kNL * 262144);
  hipLaunchKernelGGL(pack_bias_k, dim3((kNL * 384 + 255) / 256), dim3(256), 0, stream,
                     eso_b, eaw_b, fbias_e);
  hipLaunchKernelGGL(pack_bias_k, dim3((kNL * 384 + 255) / 256), dim3(256), 0, stream,
                     dso_b, daw_b, fbias_d);
  const int n4full = kBS * 64;
  hipLaunchKernelGGL(cast_bf_k, dim3((n4full + 255) / 256), dim3(256), 0, stream,
                     src, memory_bf, n4full);
  hipLaunchKernelGGL(poslev_k, dim3((n4full + 255) / 256), dim3(256), 0, stream,
                     pos, lev, poslev_bf, n4full);
  hipLaunchKernelGGL(refs_k, dim3((kS + 255) / 256), dim3(256), 0, stream, refS);
  hipLaunchKernelGGL(enc_q_k, dim3((n4full + 255) / 256), dim3(256), 0, stream,
                     src, poslev_bf, qbuf_bf, n4full);

  const int grid_ln = (kBS + 31) / 32;   // 831
  // ---- encoder ----
  for (int i = 0; i < kNL; ++i) {
    GEMM(memory_bf, evpW + (size_t)i * 65536, evp_b + i * kC, val_bf, kBS, 256, 256, 2);
    GEMM(qbuf_bf, fesoawW + (size_t)i * 98304, fbias_e + i * 384, foab_bf, kBS, 384, 256, 2);
    hipLaunchKernelGGL(msda_fused_k, dim3(kBS / 2), dim3(256), 0, stream,
                       val_bf, 512, 0, foab_bf, refS, sampbuf_bf, kS);
    hipLaunchKernelGGL((gemm_ln_k<0, 0>), dim3(grid_ln), dim3(256), 0, stream,
                       sampbuf_bf, eopW + (size_t)i * 65536, eop_b + i * kC,
                       memory_bf, en1_g + i * kC, en1_b + i * kC,
                       (float*)nullptr, memory_bf, (unsigned short*)nullptr,
                       (const unsigned short*)nullptr, kBS, 256);
    GEMM(memory_bf, el1W + (size_t)i * 262144, el1_b + i * kFF, hid_bf, kBS, 1024, 256, 1);
    hipLaunchKernelGGL((gemm_ln_k<1, 0>), dim3(grid_ln), dim3(256), 0, stream,
                       hid_bf, el2W + (size_t)i * 262144, el2_b + i * kC,
                       memory_bf, en2_g + i * kC, en2_b + i * kC,
                       (float*)nullptr, memory_bf, qbuf_bf, poslev_bf, kBS, 1024);
  }

  // ---- decoder init ----
  hipLaunchKernelGGL(dec_init_k, dim3(300), dim3(256), 0, stream, qe, tgt, tgt_bf, qposb);
  hipLaunchKernelGGL(ref_k, dim3(kNQ), dim3(64), 0, stream, qposb, refp_w, refp_b, ref300);
  GEMM(memory_bf, dvpW, dvp_b, val_all, kBS, kNL * 256, 256, 2);

  const int dn4 = kB * kNQ * 64;
  const int qn4 = kNQ * 64;
  const int MD = kB * kNQ;
  const int grid_lnd = (MD + 31) / 32;   // 19
  // ---- decoder ----
  for (int i = 0; i < kNL; ++i) {
    hipLaunchKernelGGL(add_bcast_bf_k, dim3((dn4 + 255) / 256), dim3(256), 0, stream,
                       tgt, qposb, dq_bf, dn4, qn4);
    GEMMS(dq_bf, dsaiW + (size_t)i * 196608, dsa_in_b + i * 768, qkbuf, MD, 512, 256, 0);
    GEMMS(tgt_bf, dsaiW + (size_t)i * 196608 + (size_t)512 * 256,
          dsa_in_b + i * 768 + 512, vbuf, MD, 256, 256, 0);
    hipLaunchKernelGGL(dec_attn_k, dim3(kB * kH * kNQ), dim3(64), 0, stream,
                       qkbuf, vbuf, sabuf_bf);
    hipLaunchKernelGGL((gemm_ln_k<0, 1>), dim3(grid_lnd), dim3(256), 0, stream,
                       sabuf_bf, dsaoW + (size_t)i * 65536, dsa_out_b + i * kC,
                       tgt_bf, dn2_g + i * kC, dn2_b + i * kC,
                       tgt, tgt_bf, (unsigned short*)nullptr,
                       (const unsigned short*)nullptr, MD, 256);
    hipLaunchKernelGGL(add_bcast_bf_k, dim3((dn4 + 255) / 256), dim3(256), 0, stream,
                       tgt, qposb, dq_bf, dn4, qn4);
    GEMMS(dq_bf, fdsoawW + (size_t)i * 98304, fbias_d + i * 384, dfoab_bf, MD, 384, 256, 2);
    hipLaunchKernelGGL(msda_fused_k, dim3(MD / 2), dim3(256), 0, stream,
                       val_all, kNL * 512, i * 512, dfoab_bf, ref300, dsamp_bf, kNQ);
    hipLaunchKernelGGL((gemm_ln_k<0, 1>), dim3(grid_lnd), dim3(256), 0, stream,
                       dsamp_bf, dopW + (size_t)i * 65536, dop_b + i * kC,
                       tgt_bf, dn1_g + i * kC, dn1_b + i * kC,
                       tgt, tgt_bf, (unsigned short*)nullptr,
                       (const unsigned short*)nullptr, MD, 256);
    GEMMS(tgt_bf, dl1W + (size_t)i * 262144, dl1_b + i * kFF, dffnh_bf, MD, 1024, 256, 1);
    hipLaunchKernelGGL((gemm_ln_k<0, 1>), dim3(grid_lnd), dim3(256), 0, stream,
                       dffnh_bf, dl2W + (size_t)i * 262144, dl2_b + i * kC,
                       tgt_bf, dn3_g + i * kC, dn3_b + i * kC,
                       tgt, tgt_bf, (unsigned short*)nullptr,
                       (const unsigned short*)nullptr, MD, 1024);
  }

  hipMemcpyAsync(d_out, tgt, NQC * sizeof(float), hipMemcpyDeviceToDevice, stream);
  hipLaunchKernelGGL(write_refs_k, dim3(5), dim3(256), 0, stream, ref300, (float*)d_out);
}

// Round 13
// 1692.623 us; speedup vs baseline: 1.1999x; 1.0318x over previous
//
#include <hip/hip_runtime.h>

static constexpr int kS  = 13294;
static constexpr int kB  = 2;
static constexpr int kBS = kB * kS;     // 26588
static constexpr int kC  = 256;
static constexpr int kH  = 8;
static constexpr int kNQ = 300;
static constexpr int kFF = 1024;
static constexpr int kNL = 6;

using short8 = __attribute__((ext_vector_type(8))) short;
using f32x4  = __attribute__((ext_vector_type(4))) float;

__device__ __forceinline__ unsigned short f2b(float f) {
  unsigned u = __builtin_bit_cast(unsigned, f);
  return (unsigned short)((u + 0x7FFF + ((u >> 16) & 1)) >> 16);
}
__device__ __forceinline__ float bf2f(unsigned short u) {
  return __builtin_bit_cast(float, ((unsigned)u) << 16);
}
__device__ __forceinline__ float bflo(unsigned u) {
  return __builtin_bit_cast(float, u << 16);
}
__device__ __forceinline__ float bfhi(unsigned u) {
  return __builtin_bit_cast(float, u & 0xFFFF0000u);
}

#if defined(__has_builtin)
#if __has_builtin(__builtin_amdgcn_global_load_lds)
#define HAS_GLL 1
#endif
#endif
#ifndef HAS_GLL
#define HAS_GLL 0
#endif

#if HAS_GLL
typedef const __attribute__((address_space(1))) void* gas_t;
typedef __attribute__((address_space(3))) void* las_t;
#define GLOAD16(gp, lp) __builtin_amdgcn_global_load_lds((gas_t)(gp), (las_t)(lp), 16, 0, 0)
#endif

// LDS XOR swizzle (T2, rule #21): linear LDS dest; global SOURCE column permuted by
// granule' = granule ^ (row & mask); reads apply the same XOR. Pure involution per row.

// ---------------- bf16 MFMA GEMM (128x128 tile, XCD-chunked 1-D grid) ----------------
template<int ACT, int OBF>
__global__ __launch_bounds__(256) void gemm_mfma(
    const unsigned short* __restrict__ A, const unsigned short* __restrict__ Wt,
    const float* __restrict__ bias, void* __restrict__ outp, int M, int N, int K) {
  __shared__ __align__(16) unsigned short As[128 * 64];
  __shared__ __align__(16) unsigned short Bs[128 * 64];
  const int t = threadIdx.x;
  const int nB = N >> 7;
  const int tot = gridDim.x;
  const int q8 = tot >> 3, r8 = tot & 7;
  const int xcd = blockIdx.x & 7, pos = blockIdx.x >> 3;
  const int wg = (xcd < r8 ? xcd * (q8 + 1) : r8 * (q8 + 1) + (xcd - r8) * q8) + pos;
  const int m0 = (wg / nB) * 128, n0 = (wg % nB) * 128;
  const int wid = t >> 6, lane = t & 63;
  const int wr = wid >> 1, wc = wid & 1;
  const int srow = t >> 3;
  const int scol = (((t & 7) ^ (srow & 7)) * 8);   // swizzled source column
  const int lr = lane & 15;
  const int q4 = lane >> 4;
  const int e7 = lr & 7;

  f32x4 acc[4][4];
#pragma unroll
  for (int i = 0; i < 4; ++i)
#pragma unroll
    for (int j = 0; j < 4; ++j) acc[i][j] = (f32x4){0.f, 0.f, 0.f, 0.f};

  for (int k0 = 0; k0 < K; k0 += 64) {
#if HAS_GLL
    __syncthreads();
#pragma unroll
    for (int c = 0; c < 4; ++c) {
      int ar = m0 + c * 32 + srow; if (ar >= M) ar = M - 1;
      GLOAD16(A + (size_t)ar * K + k0 + scol, (char*)As + c * 4096 + t * 16);
      int br = n0 + c * 32 + srow; if (br >= N) br = N - 1;
      GLOAD16(Wt + (size_t)br * K + k0 + scol, (char*)Bs + c * 4096 + t * 16);
    }
    __syncthreads();
#else
    short8 ta[4], tb[4];
#pragma unroll
    for (int c = 0; c < 4; ++c) {
      int ar = m0 + c * 32 + srow; if (ar >= M) ar = M - 1;
      ta[c] = *(const short8*)(A + (size_t)ar * K + k0 + scol);
      int br = n0 + c * 32 + srow; if (br >= N) br = N - 1;
      tb[c] = *(const short8*)(Wt + (size_t)br * K + k0 + scol);
    }
    __syncthreads();
#pragma unroll
    for (int c = 0; c < 4; ++c) {
      *(short8*)&As[c * 2048 + t * 8] = ta[c];
      *(short8*)&Bs[c * 2048 + t * 8] = tb[c];
    }
    __syncthreads();
#endif
#pragma unroll
    for (int kk = 0; kk < 2; ++kk) {
      const int pg = (((kk << 2) + q4) ^ e7) * 8;
      short8 af[4], bf[4];
#pragma unroll
      for (int mi = 0; mi < 4; ++mi)
        af[mi] = *(const short8*)&As[(wr * 64 + mi * 16 + lr) * 64 + pg];
#pragma unroll
      for (int ni = 0; ni < 4; ++ni)
        bf[ni] = *(const short8*)&Bs[(wc * 64 + ni * 16 + lr) * 64 + pg];
#pragma unroll
      for (int mi = 0; mi < 4; ++mi)
#pragma unroll
        for (int ni = 0; ni < 4; ++ni)
          acc[mi][ni] = __builtin_amdgcn_mfma_f32_16x16x32_bf16(af[mi], bf[ni], acc[mi][ni], 0, 0, 0);
    }
  }
  const int orow0 = m0 + wr * 64;
  const int ocol = n0 + wc * 64 + lr;
  float bv[4];
#pragma unroll
  for (int ni = 0; ni < 4; ++ni) bv[ni] = bias[ocol + ni * 16];
#pragma unroll
  for (int mi = 0; mi < 4; ++mi) {
#pragma unroll
    for (int j = 0; j < 4; ++j) {
      const int r = orow0 + mi * 16 + q4 * 4 + j;
      if (r < M) {
#pragma unroll
        for (int ni = 0; ni < 4; ++ni) {
          float v = acc[mi][ni][j] + bv[ni];
          if (ACT) v = fmaxf(v, 0.f);
          if (OBF) ((unsigned short*)outp)[(size_t)r * N + ocol + ni * 16] = f2b(v);
          else     ((float*)outp)[(size_t)r * N + ocol + ni * 16] = v;
        }
      }
    }
  }
}

// ---------------- small-tile GEMM (64x64); CORR adds row-indexed correction [kNQ, cld] ----------------
template<int ACT, int OBF, int CORR>
__global__ __launch_bounds__(256) void gemm_mfma_s(
    const unsigned short* __restrict__ A, const unsigned short* __restrict__ Wt,
    const float* __restrict__ bias, void* __restrict__ outp, int M, int N, int K,
    const float* __restrict__ corr, int cld) {
  __shared__ __align__(16) unsigned short As[64 * 64];
  __shared__ __align__(16) unsigned short Bs[64 * 64];
  const int t = threadIdx.x;
  const int m0 = blockIdx.y * 64, n0 = blockIdx.x * 64;
  const int wid = t >> 6, lane = t & 63;
  const int wr = wid >> 1, wc = wid & 1;
  const int srow = t >> 3;
  const int scol = (((t & 7) ^ (srow & 7)) * 8);
  const int lr = lane & 15;
  const int q4 = lane >> 4;
  const int e7 = lr & 7;

  f32x4 acc[2][2];
#pragma unroll
  for (int i = 0; i < 2; ++i)
#pragma unroll
    for (int j = 0; j < 2; ++j) acc[i][j] = (f32x4){0.f, 0.f, 0.f, 0.f};

  for (int k0 = 0; k0 < K; k0 += 64) {
#if HAS_GLL
    __syncthreads();
#pragma unroll
    for (int c = 0; c < 2; ++c) {
      int ar = m0 + c * 32 + srow; if (ar >= M) ar = M - 1;
      GLOAD16(A + (size_t)ar * K + k0 + scol, (char*)As + c * 4096 + t * 16);
      int br = n0 + c * 32 + srow; if (br >= N) br = N - 1;
      GLOAD16(Wt + (size_t)br * K + k0 + scol, (char*)Bs + c * 4096 + t * 16);
    }
    __syncthreads();
#else
    short8 ta[2], tb[2];
#pragma unroll
    for (int c = 0; c < 2; ++c) {
      int ar = m0 + c * 32 + srow; if (ar >= M) ar = M - 1;
      ta[c] = *(const short8*)(A + (size_t)ar * K + k0 + scol);
      int br = n0 + c * 32 + srow; if (br >= N) br = N - 1;
      tb[c] = *(const short8*)(Wt + (size_t)br * K + k0 + scol);
    }
    __syncthreads();
#pragma unroll
    for (int c = 0; c < 2; ++c) {
      *(short8*)&As[c * 2048 + t * 8] = ta[c];
      *(short8*)&Bs[c * 2048 + t * 8] = tb[c];
    }
    __syncthreads();
#endif
#pragma unroll
    for (int kk = 0; kk < 2; ++kk) {
      const int pg = (((kk << 2) + q4) ^ e7) * 8;
      short8 af[2], bf[2];
#pragma unroll
      for (int mi = 0; mi < 2; ++mi)
        af[mi] = *(const short8*)&As[(wr * 32 + mi * 16 + lr) * 64 + pg];
#pragma unroll
      for (int ni = 0; ni < 2; ++ni)
        bf[ni] = *(const short8*)&Bs[(wc * 32 + ni * 16 + lr) * 64 + pg];
#pragma unroll
      for (int mi = 0; mi < 2; ++mi)
#pragma unroll
        for (int ni = 0; ni < 2; ++ni)
          acc[mi][ni] = __builtin_amdgcn_mfma_f32_16x16x32_bf16(af[mi], bf[ni], acc[mi][ni], 0, 0, 0);
    }
  }
  const int orow0 = m0 + wr * 32;
  const int ocol = n0 + wc * 32 + lr;
  float bv[2];
#pragma unroll
  for (int ni = 0; ni < 2; ++ni) bv[ni] = CORR ? 0.f : bias[ocol + ni * 16];
#pragma unroll
  for (int mi = 0; mi < 2; ++mi) {
#pragma unroll
    for (int j = 0; j < 4; ++j) {
      const int r = orow0 + mi * 16 + q4 * 4 + j;
      if (r < M) {
        const float* cr = CORR ? (corr + (size_t)(r < kNQ ? r : r - kNQ) * cld) : nullptr;
#pragma unroll
        for (int ni = 0; ni < 2; ++ni) {
          float v = acc[mi][ni][j] + (CORR ? cr[ocol + ni * 16] : bv[ni]);
          if (ACT) v = fmaxf(v, 0.f);
          if (OBF) ((unsigned short*)outp)[(size_t)r * N + ocol + ni * 16] = f2b(v);
          else     ((float*)outp)[(size_t)r * N + ocol + ni * 16] = v;
        }
      }
    }
  }
}

// ---------------- fused GEMM + residual(bf16) + LayerNorm (BM=32, N=256, BK=128) ----------------
template<int WRITEQ, int WRITEF>
__global__ __launch_bounds__(256) void gemm_ln_k(
    const unsigned short* __restrict__ A, const unsigned short* __restrict__ Wt,
    const float* __restrict__ bias, const unsigned short* __restrict__ x_bf,
    const float* __restrict__ g, const float* __restrict__ be,
    float* __restrict__ outf, unsigned short* __restrict__ outb,
    unsigned short* __restrict__ qout, const unsigned short* __restrict__ poslev,
    int M, int K) {
  __shared__ __align__(16) unsigned short As[32 * 128];     // 8 KB
  __shared__ __align__(16) unsigned short Bs[256 * 128];    // 64 KB
  __shared__ float rsum[32][4], rsq[32][4], rmv[32][2];
  const int t = threadIdx.x;
  const int m0 = blockIdx.x * 32;
  const int wid = t >> 6, lane = t & 63;
  const int lr = lane & 15;
  const int q4 = lane >> 4;
  const int t16 = t >> 4;
  const int g16 = (t & 15) ^ t16;

  f32x4 acc[2][4];
#pragma unroll
  for (int i = 0; i < 2; ++i)
#pragma unroll
    for (int j = 0; j < 4; ++j) acc[i][j] = (f32x4){0.f, 0.f, 0.f, 0.f};

  for (int k0 = 0; k0 < K; k0 += 128) {
#if HAS_GLL
    __syncthreads();
#pragma unroll
    for (int c = 0; c < 2; ++c) {
      int ar = m0 + c * 16 + t16; if (ar >= M) ar = M - 1;
      GLOAD16(A + (size_t)ar * K + k0 + g16 * 8, (char*)As + c * 4096 + t * 16);
    }
#pragma unroll
    for (int c = 0; c < 16; ++c) {
      const int br = c * 16 + t16;
      GLOAD16(Wt + (size_t)br * K + k0 + g16 * 8, (char*)Bs + c * 4096 + t * 16);
    }
    __syncthreads();
#else
    short8 ta[2], tb[16];
#pragma unroll
    for (int c = 0; c < 2; ++c) {
      int ar = m0 + c * 16 + t16; if (ar >= M) ar = M - 1;
      ta[c] = *(const short8*)(A + (size_t)ar * K + k0 + g16 * 8);
    }
#pragma unroll
    for (int c = 0; c < 16; ++c)
      tb[c] = *(const short8*)(Wt + (size_t)(c * 16 + t16) * K + k0 + g16 * 8);
    __syncthreads();
#pragma unroll
    for (int c = 0; c < 2; ++c) *(short8*)&As[c * 2048 + t * 8] = ta[c];
#pragma unroll
    for (int c = 0; c < 16; ++c) *(short8*)&Bs[c * 2048 + t * 8] = tb[c];
    __syncthreads();
#endif
#pragma unroll
    for (int kk = 0; kk < 4; ++kk) {
      const int pg = (((kk << 2) + q4) ^ lr) * 8;
      short8 af[2], bf[4];
#pragma unroll
      for (int mi = 0; mi < 2; ++mi)
        af[mi] = *(const short8*)&As[(mi * 16 + lr) * 128 + pg];
#pragma unroll
      for (int ni = 0; ni < 4; ++ni)
        bf[ni] = *(const short8*)&Bs[(wid * 64 + ni * 16 + lr) * 128 + pg];
#pragma unroll
      for (int mi = 0; mi < 2; ++mi)
#pragma unroll
        for (int ni = 0; ni < 4; ++ni)
          acc[mi][ni] = __builtin_amdgcn_mfma_f32_16x16x32_bf16(af[mi], bf[ni], acc[mi][ni], 0, 0, 0);
    }
  }
  float bv[4], gv[4], bev[4];
  int cols[4];
#pragma unroll
  for (int ni = 0; ni < 4; ++ni) {
    cols[ni] = wid * 64 + ni * 16 + lr;
    bv[ni] = bias[cols[ni]];
    gv[ni] = g[cols[ni]];
    bev[ni] = be[cols[ni]];
  }
#pragma unroll
  for (int mi = 0; mi < 2; ++mi) {
#pragma unroll
    for (int j = 0; j < 4; ++j) {
      const int brow = mi * 16 + q4 * 4 + j;
      int grow = m0 + brow; if (grow >= M) grow = M - 1;
      const unsigned short* xr = x_bf + (size_t)grow * 256;
      float s = 0.f, s2 = 0.f;
#pragma unroll
      for (int ni = 0; ni < 4; ++ni) {
        float v = acc[mi][ni][j] + bv[ni] + bf2f(xr[cols[ni]]);
        acc[mi][ni][j] = v;
        s += v; s2 += v * v;
      }
#pragma unroll
      for (int o = 1; o < 16; o <<= 1) {
        s += __shfl_xor(s, o);
        s2 += __shfl_xor(s2, o);
      }
      if (lr == 0) { rsum[brow][wid] = s; rsq[brow][wid] = s2; }
    }
  }
  __syncthreads();
  if (t < 32) {
    float s = rsum[t][0] + rsum[t][1] + rsum[t][2] + rsum[t][3];
    float s2 = rsq[t][0] + rsq[t][1] + rsq[t][2] + rsq[t][3];
    float mean = s * (1.f / 256.f);
    float var = s2 * (1.f / 256.f) - mean * mean;
    rmv[t][0] = mean;
    rmv[t][1] = rsqrtf(var + 1e-5f);
  }
  __syncthreads();
#pragma unroll
  for (int mi = 0; mi < 2; ++mi) {
#pragma unroll
    for (int j = 0; j < 4; ++j) {
      const int brow = mi * 16 + q4 * 4 + j;
      const int grow = m0 + brow;
      if (grow >= M) continue;
      const float mean = rmv[brow][0], rs = rmv[brow][1];
#pragma unroll
      for (int ni = 0; ni < 4; ++ni) {
        const float v = (acc[mi][ni][j] - mean) * rs * gv[ni] + bev[ni];
        const size_t oi = (size_t)grow * 256 + cols[ni];
        if (WRITEF) outf[oi] = v;
        outb[oi] = f2b(v);
        if (WRITEQ) qout[oi] = f2b(v + bf2f(poslev[oi]));
      }
    }
  }
}

// ---------------- casts / packs ----------------
__global__ void cast_bf_k(const float* __restrict__ in, unsigned short* __restrict__ out, int n4) {
  int i = blockIdx.x * 256 + threadIdx.x;
  if (i >= n4) return;
  float4 v = ((const float4*)in)[i];
  ushort4 o; o.x = f2b(v.x); o.y = f2b(v.y); o.z = f2b(v.z); o.w = f2b(v.w);
  ((ushort4*)out)[i] = o;
}

// fused so/aw weight pack for ALL layers: out[l][r][c], r<256 -> so_w, else aw_w (bf16)
__global__ void pack_soaw_k(const float* __restrict__ so_w, const float* __restrict__ aw_w,
                            unsigned short* __restrict__ out, int total4) {
  int i = blockIdx.x * 256 + threadIdx.x;
  if (i >= total4) return;
  int e = i * 4;
  int l = e / 98304;
  int rem = e - l * 98304;
  int r = rem >> 8;
  int c = rem & 255;
  const float* src = (r < 256) ? (so_w + (size_t)l * 65536 + r * 256 + c)
                               : (aw_w + (size_t)l * 32768 + (r - 256) * 256 + c);
  float4 v = *(const float4*)src;
  ushort4 o; o.x = f2b(v.x); o.y = f2b(v.y); o.z = f2b(v.z); o.w = f2b(v.w);
  ((ushort4*)out)[i] = o;
}

__global__ void pack_bias_k(const float* __restrict__ so_b, const float* __restrict__ aw_b,
                            float* __restrict__ fb) {
  int i = blockIdx.x * 256 + threadIdx.x;
  if (i >= kNL * 384) return;
  int l = i / 384, j = i - l * 384;
  fb[i] = (j < 256) ? so_b[l * 256 + j] : aw_b[l * 128 + j - 256];
}

// overwrite V-thirds of corrQKV with plain bias (V uses tgt, not tgt+qpos)
__global__ void corr_vfix_k(const float* __restrict__ dsa_in_b, float* __restrict__ corr) {
  int i = blockIdx.x * 256 + threadIdx.x;
  if (i >= kNQ * kNL * 256) return;
  int q = i / (kNL * 256);
  int rem = i - q * (kNL * 256);
  int l = rem >> 8, c = rem & 255;
  corr[(size_t)q * (kNL * 768) + l * 768 + 512 + c] = dsa_in_b[l * 768 + 512 + c];
}

// ---------------- poslev = bf16(pos + level_embed) ----------------
__global__ void poslev_k(const float* __restrict__ pos, const float* __restrict__ lev,
                         unsigned short* __restrict__ out, int n4) {
  int i = blockIdx.x * 256 + threadIdx.x;
  if (i >= n4) return;
  int c4 = i & 63;
  int row = i >> 6;
  int s = row % kS;
  int l = (s < 10000) ? 0 : (s < 12500) ? 1 : (s < 13125) ? 2 : 3;
  float4 p = ((const float4*)pos)[i];
  float4 lv = ((const float4*)(lev + l * kC))[c4];
  ushort4 o;
  o.x = f2b(p.x + lv.x); o.y = f2b(p.y + lv.y);
  o.z = f2b(p.z + lv.z); o.w = f2b(p.w + lv.w);
  ((ushort4*)out)[i] = o;
}

// ---------------- initial q = bf16(src + poslev) ----------------
__global__ void enc_q_k(const float* __restrict__ src, const unsigned short* __restrict__ poslev,
                        unsigned short* __restrict__ q, int n4) {
  int i = blockIdx.x * 256 + threadIdx.x;
  if (i >= n4) return;
  float4 m = ((const float4*)src)[i];
  ushort4 pl = ((const ushort4*)poslev)[i];
  ushort4 o;
  o.x = f2b(m.x + bf2f(pl.x)); o.y = f2b(m.y + bf2f(pl.y));
  o.z = f2b(m.z + bf2f(pl.z)); o.w = f2b(m.w + bf2f(pl.w));
  ((ushort4*)q)[i] = o;
}

// ---------------- encoder reference points ----------------
__global__ void refs_k(float* __restrict__ refS) {
  int s = blockIdx.x * 256 + threadIdx.x;
  if (s >= kS) return;
  int st, W;
  if (s < 10000)      { st = 0;     W = 100; }
  else if (s < 12500) { st = 10000; W = 50; }
  else if (s < 13125) { st = 12500; W = 25; }
  else                { st = 13125; W = 13; }
  int idx = s - st;
  int y = idx / W;
  int x = idx - y * W;
  refS[s * 2 + 0] = (x + 0.5f) / (float)W;
  refS[s * 2 + 1] = (y + 0.5f) / (float)W;
}

// ---------------- fused MSDA: 2 queries/block, saddr gathers, bf16 foab ----------------
__global__ __launch_bounds__(256) void msda_fused_k(
    const unsigned short* __restrict__ value, int vstride, int vcol,
    const unsigned short* __restrict__ foab, const float* __restrict__ refs,
    unsigned short* __restrict__ out, int Mq) {
  __shared__ int   sidx[16][2][kH][4];
  __shared__ float sw[16][2][kH][4];
  const int t = threadIdx.x;
  const int bq0 = blockIdx.x * 2;
  const int qq = t >> 7;
  {
    const int bq = bq0 + qq;
    const int b = (bq >= Mq) ? 1 : 0;
    const int qi = bq - b * Mq;
    const int h = (t >> 4) & 7, lp = t & 15, l = lp >> 2;
    const unsigned short* row = foab + (size_t)bq * 384;
    float logit = bf2f(row[256 + h * 16 + lp]);
    float mx = logit;
#pragma unroll
    for (int o = 1; o < 16; o <<= 1) mx = fmaxf(mx, __shfl_xor(mx, o));
    float e = __expf(logit - mx), ssum = e;
#pragma unroll
    for (int o = 1; o < 16; o <<= 1) ssum += __shfl_xor(ssum, o);
    const float a = e / ssum;
    const unsigned opair = *(const unsigned*)(row + h * 32 + lp * 2);
    const float offx = bflo(opair);
    const float offy = bfhi(opair);
    const float rx = refs[qi * 2 + 0];
    const float ry = refs[qi * 2 + 1];
    const int wtab[4] = {100, 50, 25, 13};
    const int stab[4] = {0, 10000, 12500, 13125};
    const int W = wtab[l];
    const int start = stab[l];
    const float px = fmaf(rx, (float)W, offx) - 0.5f;
    const float py = fmaf(ry, (float)W, offy) - 0.5f;
    const float fx = floorf(px), fy = floorf(py);
    const float wx = px - fx, wy = py - fy;
    const int x0 = (int)fx, y0 = (int)fy;
    const int x0c = min(max(x0, 0), W - 1);
    const int x1c = min(max(x0 + 1, 0), W - 1);
    const int y0c = min(max(y0, 0), W - 1);
    const int y1c = min(max(y0 + 1, 0), W - 1);
    const float vx0 = (x0 >= 0 && x0 < W) ? 1.f : 0.f;
    const float vx1 = (x0 + 1 >= 0 && x0 + 1 < W) ? 1.f : 0.f;
    const float vy0 = (y0 >= 0 && y0 < W) ? 1.f : 0.f;
    const float vy1 = (y0 + 1 >= 0 && y0 + 1 < W) ? 1.f : 0.f;
    const int base0 = b * kS * vstride + vcol + start * vstride;
    sidx[lp][qq][h][0] = base0 + (y0c * W + x0c) * vstride;
    sidx[lp][qq][h][1] = base0 + (y0c * W + x1c) * vstride;
    sidx[lp][qq][h][2] = base0 + (y1c * W + x0c) * vstride;
    sidx[lp][qq][h][3] = base0 + (y1c * W + x1c) * vstride;
    const float omwx = 1.f - wx, omwy = 1.f - wy;
    sw[lp][qq][h][0] = a * omwy * omwx * vy0 * vx0;
    sw[lp][qq][h][1] = a * omwy * wx * vy0 * vx1;
    sw[lp][qq][h][2] = a * wy * omwx * vy1 * vx0;
    sw[lp][qq][h][3] = a * wy * wx * vy1 * vx1;
  }
  __syncthreads();
  const int h = (t >> 4) & 7, dp = t & 15;
  const int bq = bq0 + qq;
  const int chan = h * 64 + dp * 4;
  const char* valc = (const char*)value;
  float aLo0 = 0.f, aLo1 = 0.f, aHi0 = 0.f, aHi1 = 0.f;
#pragma unroll
  for (int p0 = 0; p0 < 16; p0 += 8) {
    unsigned u[32];
    float w[32];
#pragma unroll
    for (int pp = 0; pp < 8; ++pp) {
      const int4 I = *(const int4*)&sidx[p0 + pp][qq][h][0];
      const float4 Wv = *(const float4*)&sw[p0 + pp][qq][h][0];
      u[pp * 4 + 0] = *(const unsigned*)(valc + (unsigned)(I.x + chan));
      u[pp * 4 + 1] = *(const unsigned*)(valc + (unsigned)(I.y + chan));
      u[pp * 4 + 2] = *(const unsigned*)(valc + (unsigned)(I.z + chan));
      u[pp * 4 + 3] = *(const unsigned*)(valc + (unsigned)(I.w + chan));
      w[pp * 4 + 0] = Wv.x; w[pp * 4 + 1] = Wv.y;
      w[pp * 4 + 2] = Wv.z; w[pp * 4 + 3] = Wv.w;
    }
#pragma unroll
    for (int j = 0; j < 32; j += 2) {
      aLo0 = fmaf(w[j], bflo(u[j]), aLo0);
      aHi0 = fmaf(w[j], bfhi(u[j]), aHi0);
      aLo1 = fmaf(w[j + 1], bflo(u[j + 1]), aLo1);
      aHi1 = fmaf(w[j + 1], bfhi(u[j + 1]), aHi1);
    }
  }
  const float accLo = aLo0 + aLo1;
  const float accHi = aHi0 + aHi1;
  const unsigned packed = (unsigned)f2b(accLo) | ((unsigned)f2b(accHi) << 16);
  ((unsigned*)out)[(size_t)bq * 128 + h * 16 + dp] = packed;
}

// ---------------- decoder init: tgt (f32+bf16), qpos (f32+bf16) ----------------
__global__ void dec_init_k(const float* __restrict__ qe, float* __restrict__ tgt,
                           unsigned short* __restrict__ tgt_bf, float* __restrict__ qposb,
                           unsigned short* __restrict__ qpos_bf) {
  int i = blockIdx.x * 256 + threadIdx.x;
  if (i >= kNQ * kC) return;
  int q = i >> 8, c = i & 255;
  float qp = qe[q * 512 + c];
  qposb[i] = qp;
  qpos_bf[i] = f2b(qp);
  float tg = qe[q * 512 + 256 + c];
  tgt[i] = tg;
  tgt[kNQ * kC + i] = tg;
  unsigned short tb = f2b(tg);
  tgt_bf[i] = tb;
  tgt_bf[kNQ * kC + i] = tb;
}

// ---------------- ref300 ----------------
__global__ __launch_bounds__(64) void ref_k(const float* __restrict__ qposb,
                                            const float* __restrict__ rw,
                                            const float* __restrict__ rb,
                                            float* __restrict__ ref300) {
  const int q = blockIdx.x;
  const int lane = threadIdx.x;
  const float4 qv = ((const float4*)(qposb + q * 256))[lane];
  const float4 w0 = ((const float4*)rw)[lane];
  const float4 w1 = ((const float4*)(rw + 256))[lane];
  float a0 = qv.x * w0.x + qv.y * w0.y + qv.z * w0.z + qv.w * w0.w;
  float a1 = qv.x * w1.x + qv.y * w1.y + qv.z * w1.z + qv.w * w1.w;
#pragma unroll
  for (int off = 32; off; off >>= 1) {
    a0 += __shfl_xor(a0, off);
    a1 += __shfl_xor(a1, off);
  }
  if (lane == 0) {
    ref300[q * 2 + 0] = 1.f / (1.f + __expf(-(a0 + rb[0])));
    ref300[q * 2 + 1] = 1.f / (1.f + __expf(-(a1 + rb[1])));
  }
}

// ---------------- decoder self-attention (QKV packed [B*NQ, 768]) ----------------
__global__ __launch_bounds__(64) void dec_attn_k(const float* __restrict__ qkv,
                                                 unsigned short* __restrict__ outp) {
  const int bid = blockIdx.x;
  const int q = bid % kNQ;
  const int bh = bid / kNQ;
  const int h = bh & 7;
  const int b = bh >> 3;
  const int lane = threadIdx.x;
  __shared__ float p[304];
  const float* qv = qkv + (size_t)(b * kNQ + q) * 768 + h * 32;
  float qreg[32];
#pragma unroll
  for (int m = 0; m < 32; ++m) qreg[m] = qv[m];
  float scores[5];
  float mx = -1e30f;
#pragma unroll
  for (int j = 0; j < 5; ++j) {
    const int k = lane + j * 64;
    float sc = -1e30f;
    if (k < kNQ) {
      const float* kv = qkv + (size_t)(b * kNQ + k) * 768 + 256 + h * 32;
      float acc = 0.f;
#pragma unroll
      for (int m = 0; m < 32; ++m) acc = fmaf(qreg[m], kv[m], acc);
      sc = acc * 0.17677669529663687f;
    }
    scores[j] = sc;
    mx = fmaxf(mx, sc);
  }
#pragma unroll
  for (int off = 32; off; off >>= 1) mx = fmaxf(mx, __shfl_xor(mx, off));
  float sum = 0.f;
#pragma unroll
  for (int j = 0; j < 5; ++j) {
    const int k = lane + j * 64;
    float e = 0.f;
    if (k < kNQ) e = __expf(scores[j] - mx);
    scores[j] = e;
    sum += e;
  }
#pragma unroll
  for (int off = 32; off; off >>= 1) sum += __shfl_xor(sum, off);
  const float inv = 1.f / sum;
#pragma unroll
  for (int j = 0; j < 5; ++j) {
    const int k = lane + j * 64;
    if (k < kNQ) p[k] = scores[j] * inv;
  }
  __syncthreads();
  const int d = lane & 31, half = lane >> 5;
  float acc = 0.f;
  for (int k = half * 150; k < half * 150 + 150; ++k)
    acc = fmaf(p[k], qkv[(size_t)(b * kNQ + k) * 768 + 512 + h * 32 + d], acc);
  acc += __shfl_down(acc, 32);
  if (lane < 32) outp[((size_t)(b * kNQ + q)) * 256 + h * 32 + d] = f2b(acc);
}

// ---------------- write init_ref / ref outputs ----------------
__global__ void write_refs_k(const float* __restrict__ ref300, float* __restrict__ outp) {
  int i = blockIdx.x * 256 + threadIdx.x;
  if (i >= 1200) return;
  float v = ref300[i % 600];
  outp[153600 + i] = v;
  outp[154800 + i] = v;
}

__global__ void sentinel_k(float* __restrict__ outp) {
  if (threadIdx.x < 64) outp[threadIdx.x] = 12345.0f;
}

extern "C" void kernel_launch(void* const* d_in, const int* in_sizes, int n_in,
                              void* d_out, int out_size, void* d_ws, size_t ws_size,
                              hipStream_t stream) {
  const float* src      = (const float*)d_in[0];
  const float* pos      = (const float*)d_in[1];
  const float* qe       = (const float*)d_in[2];
  const float* lev      = (const float*)d_in[3];
  const float* refp_w   = (const float*)d_in[4];
  const float* refp_b   = (const float*)d_in[5];
  const float* eso_w    = (const float*)d_in[6];
  const float* eso_b    = (const float*)d_in[7];
  const float* eaw_w    = (const float*)d_in[8];
  const float* eaw_b    = (const float*)d_in[9];
  const float* evp_w    = (const float*)d_in[10];
  const float* evp_b    = (const float*)d_in[11];
  const float* eop_w    = (const float*)d_in[12];
  const float* eop_b    = (const float*)d_in[13];
  const float* en1_g    = (const float*)d_in[14];
  const float* en1_b    = (const float*)d_in[15];
  const float* el1_w    = (const float*)d_in[16];
  const float* el1_b    = (const float*)d_in[17];
  const float* el2_w    = (const float*)d_in[18];
  const float* el2_b    = (const float*)d_in[19];
  const float* en2_g    = (const float*)d_in[20];
  const float* en2_b    = (const float*)d_in[21];
  const float* dso_w    = (const float*)d_in[22];
  const float* dso_b    = (const float*)d_in[23];
  const float* daw_w    = (const float*)d_in[24];
  const float* daw_b    = (const float*)d_in[25];
  const float* dvp_w    = (const float*)d_in[26];
  const float* dvp_b    = (const float*)d_in[27];
  const float* dop_w    = (const float*)d_in[28];
  const float* dop_b    = (const float*)d_in[29];
  const float* dsa_in_w = (const float*)d_in[30];
  const float* dsa_in_b = (const float*)d_in[31];
  const float* dsa_out_w= (const float*)d_in[32];
  const float* dsa_out_b= (const float*)d_in[33];
  const float* dn1_g    = (const float*)d_in[34];
  const float* dn1_b    = (const float*)d_in[35];
  const float* dn2_g    = (const float*)d_in[36];
  const float* dn2_b    = (const float*)d_in[37];
  const float* dn3_g    = (const float*)d_in[38];
  const float* dn3_b    = (const float*)d_in[39];
  const float* dl1_w    = (const float*)d_in[40];
  const float* dl1_b    = (const float*)d_in[41];
  const float* dl2_w    = (const float*)d_in[42];
  const float* dl2_b    = (const float*)d_in[43];

  float* Wsp = (float*)d_ws;
  size_t off = 0;
  auto alloc = [&](size_t n) { float* p = Wsp + off; off += n; return p; };
  const size_t NBC = (size_t)kBS * kC;           // 6,806,528
  unsigned short* memory_bf = (unsigned short*)alloc(NBC / 2);
  unsigned short* poslev_bf = (unsigned short*)alloc(NBC / 2);
  float* r2       = alloc(NBC);
  unsigned short* val_bf = (unsigned short*)r2;
  float* r3       = alloc(NBC / 2);
  unsigned short* qbuf_bf = (unsigned short*)r3;
  unsigned short* sampbuf_bf = (unsigned short*)r3;
  float* r4       = alloc(NBC * 2);
  unsigned short* foab_bf = (unsigned short*)r4;
  unsigned short* hid_bf = (unsigned short*)r4;
  unsigned short* val_all = (unsigned short*)r2;   // decoder overlay [kBS,1536]
  float* refS     = alloc((size_t)kS * 2 + 2);
  auto allocb = [&](size_t elems) { return (unsigned short*)alloc(elems / 2); };
  unsigned short* fesoawW = allocb((size_t)kNL * 384 * 256);
  unsigned short* evpW  = allocb((size_t)kNL * 65536);
  unsigned short* eopW  = allocb((size_t)kNL * 65536);
  unsigned short* el1W  = allocb((size_t)kNL * 262144);
  unsigned short* el2W  = allocb((size_t)kNL * 262144);
  unsigned short* fdsoawW = allocb((size_t)kNL * 384 * 256);
  unsigned short* dvpW  = allocb((size_t)kNL * 65536);
  unsigned short* dopW  = allocb((size_t)kNL * 65536);
  unsigned short* dsaiW = allocb((size_t)kNL * 196608);
  unsigned short* dsaoW = allocb((size_t)kNL * 65536);
  unsigned short* dl1W  = allocb((size_t)kNL * 262144);
  unsigned short* dl2W  = allocb((size_t)kNL * 262144);
  float* fbias_e  = alloc((size_t)kNL * 384);
  float* fbias_d  = alloc((size_t)kNL * 384);
  const size_t NQC = (size_t)kB * kNQ * kC;       // 153,600
  float* tgt      = alloc(NQC);
  unsigned short* tgt_bf = (unsigned short*)alloc(NQC / 2);
  float* qposb    = alloc((size_t)kNQ * kC);
  unsigned short* qpos_bf = (unsigned short*)alloc((size_t)kNQ * kC / 2);
  float* qkvbuf   = alloc((size_t)kB * kNQ * 768);
  unsigned short* sabuf_bf = (unsigned short*)alloc(NQC / 2);
  unsigned short* dfoab_bf = (unsigned short*)alloc((size_t)kB * kNQ * 384 / 2);
  unsigned short* dsamp_bf = (unsigned short*)alloc(NQC / 2);
  unsigned short* dffnh_bf = (unsigned short*)alloc((size_t)kB * kNQ * kFF / 2);
  float* corrQKV  = alloc((size_t)kNQ * kNL * 768);   // [300, 4608]
  float* corrSOAW = alloc((size_t)kNQ * kNL * 384);   // [300, 2304]
  float* ref300   = alloc(600);

  if (ws_size < off * sizeof(float)) {
    hipLaunchKernelGGL(sentinel_k, dim3(1), dim3(64), 0, stream, (float*)d_out);
    return;
  }

  auto GEMM = [&](const unsigned short* A, const unsigned short* Wt, const float* bias,
                  void* out, int M, int N, int K, int variant) {
    dim3 g((N / 128) * ((M + 127) / 128));
    if (variant == 1)
      hipLaunchKernelGGL((gemm_mfma<1, 1>), g, dim3(256), 0, stream, A, Wt, bias, out, M, N, K);
    else if (variant == 2)
      hipLaunchKernelGGL((gemm_mfma<0, 1>), g, dim3(256), 0, stream, A, Wt, bias, out, M, N, K);
    else
      hipLaunchKernelGGL((gemm_mfma<0, 0>), g, dim3(256), 0, stream, A, Wt, bias, out, M, N, K);
  };
  auto CASTW = [&](const float* srcw, unsigned short* dstw, size_t elems) {
    int n4 = (int)(elems / 4);
    hipLaunchKernelGGL(cast_bf_k, dim3((n4 + 255) / 256), dim3(256), 0, stream, srcw, dstw, n4);
  };

  // ---- setup ----
  {
    const int tot4 = kNL * 98304 / 4;  // 147456
    hipLaunchKernelGGL(pack_soaw_k, dim3((tot4 + 255) / 256), dim3(256), 0, stream,
                       eso_w, eaw_w, fesoawW, tot4);
    hipLaunchKernelGGL(pack_soaw_k, dim3((tot4 + 255) / 256), dim3(256), 0, stream,
                       dso_w, daw_w, fdsoawW, tot4);
  }
  CASTW(evp_w, evpW, (size_t)kNL * 65536);
  CASTW(eop_w, eopW, (size_t)kNL * 65536);
  CASTW(el1_w, el1W, (size_t)kNL * 262144);
  CASTW(el2_w, el2W, (size_t)kNL * 262144);
  CASTW(dvp_w, dvpW, (size_t)kNL * 65536);
  CASTW(dop_w, dopW, (size_t)kNL * 65536);
  CASTW(dsa_in_w, dsaiW, (size_t)kNL * 196608);
  CASTW(dsa_out_w, dsaoW, (size_t)kNL * 65536);
  CASTW(dl1_w, dl1W, (size_t)kNL * 262144);
  CASTW(dl2_w, dl2W, (size_t)kNL * 262144);
  hipLaunchKernelGGL(pack_bias_k, dim3((kNL * 384 + 255) / 256), dim3(256), 0, stream,
                     eso_b, eaw_b, fbias_e);
  hipLaunchKernelGGL(pack_bias_k, dim3((kNL * 384 + 255) / 256), dim3(256), 0, stream,
                     dso_b, daw_b, fbias_d);
  const int n4full = kBS * 64;
  hipLaunchKernelGGL(cast_bf_k, dim3((n4full + 255) / 256), dim3(256), 0, stream,
                     src, memory_bf, n4full);
  hipLaunchKernelGGL(poslev_k, dim3((n4full + 255) / 256), dim3(256), 0, stream,
                     pos, lev, poslev_bf, n4full);
  hipLaunchKernelGGL(refs_k, dim3((kS + 255) / 256), dim3(256), 0, stream, refS);
  hipLaunchKernelGGL(enc_q_k, dim3((n4full + 255) / 256), dim3(256), 0, stream,
                     src, poslev_bf, qbuf_bf, n4full);

  const int grid_ln = (kBS + 31) / 32;   // 831
  // ---- encoder ----
  for (int i = 0; i < kNL; ++i) {
    GEMM(memory_bf, evpW + (size_t)i * 65536, evp_b + i * kC, val_bf, kBS, 256, 256, 2);
    GEMM(qbuf_bf, fesoawW + (size_t)i * 98304, fbias_e + i * 384, foab_bf, kBS, 384, 256, 2);
    hipLaunchKernelGGL(msda_fused_k, dim3(kBS / 2), dim3(256), 0, stream,
                       val_bf, 512, 0, foab_bf, refS, sampbuf_bf, kS);
    hipLaunchKernelGGL((gemm_ln_k<0, 0>), dim3(grid_ln), dim3(256), 0, stream,
                       sampbuf_bf, eopW + (size_t)i * 65536, eop_b + i * kC,
                       memory_bf, en1_g + i * kC, en1_b + i * kC,
                       (float*)nullptr, memory_bf, (unsigned short*)nullptr,
                       (const unsigned short*)nullptr, kBS, 256);
    GEMM(memory_bf, el1W + (size_t)i * 262144, el1_b + i * kFF, hid_bf, kBS, 1024, 256, 1);
    hipLaunchKernelGGL((gemm_ln_k<1, 0>), dim3(grid_ln), dim3(256), 0, stream,
                       hid_bf, el2W + (size_t)i * 262144, el2_b + i * kC,
                       memory_bf, en2_g + i * kC, en2_b + i * kC,
                       (float*)nullptr, memory_bf, qbuf_bf, poslev_bf, kBS, 1024);
  }

  // ---- decoder init ----
  hipLaunchKernelGGL(dec_init_k, dim3(300), dim3(256), 0, stream, qe, tgt, tgt_bf, qposb, qpos_bf);
  hipLaunchKernelGGL(ref_k, dim3(kNQ), dim3(64), 0, stream, qposb, refp_w, refp_b, ref300);
  GEMM(memory_bf, dvpW, dvp_b, val_all, kBS, kNL * 256, 256, 2);
  // corr matrices: qpos @ W^T + bias for all layers (one GEMM each), then V-part fixup
  hipLaunchKernelGGL((gemm_mfma_s<0, 0, 0>), dim3(kNL * 768 / 64, (kNQ + 63) / 64), dim3(256), 0,
                     stream, qpos_bf, dsaiW, dsa_in_b, corrQKV, kNQ, kNL * 768, 256,
                     (const float*)nullptr, 0);
  hipLaunchKernelGGL(corr_vfix_k, dim3((kNQ * kNL * 256 + 255) / 256), dim3(256), 0, stream,
                     dsa_in_b, corrQKV);
  hipLaunchKernelGGL((gemm_mfma_s<0, 0, 0>), dim3(kNL * 384 / 64, (kNQ + 63) / 64), dim3(256), 0,
                     stream, qpos_bf, fdsoawW, fbias_d, corrSOAW, kNQ, kNL * 384, 256,
                     (const float*)nullptr, 0);

  const int MD = kB * kNQ;
  const int grid_lnd = (MD + 31) / 32;   // 19
  // ---- decoder ----
  for (int i = 0; i < kNL; ++i) {
    // fused QKV projection: Q,K get qpos-corrected rows; V gets plain bias (via corr_vfix)
    hipLaunchKernelGGL((gemm_mfma_s<0, 0, 1>), dim3(768 / 64, (MD + 63) / 64), dim3(256), 0,
                       stream, tgt_bf, dsaiW + (size_t)i * 196608, (const float*)nullptr,
                       qkvbuf, MD, 768, 256, corrQKV + (size_t)i * 768, kNL * 768);
    hipLaunchKernelGGL(dec_attn_k, dim3(kB * kH * kNQ), dim3(64), 0, stream,
                       qkvbuf, sabuf_bf);
    hipLaunchKernelGGL((gemm_ln_k<0, 1>), dim3(grid_lnd), dim3(256), 0, stream,
                       sabuf_bf, dsaoW + (size_t)i * 65536, dsa_out_b + i * kC,
                       tgt_bf, dn2_g + i * kC, dn2_b + i * kC,
                       tgt, tgt_bf, (unsigned short*)nullptr,
                       (const unsigned short*)nullptr, MD, 256);
    hipLaunchKernelGGL((gemm_mfma_s<0, 1, 1>), dim3(384 / 64, (MD + 63) / 64), dim3(256), 0,
                       stream, tgt_bf, fdsoawW + (size_t)i * 98304, (const float*)nullptr,
                       dfoab_bf, MD, 384, 256, corrSOAW + (size_t)i * 384, kNL * 384);
    hipLaunchKernelGGL(msda_fused_k, dim3(MD / 2), dim3(256), 0, stream,
                       val_all, kNL * 512, i * 512, dfoab_bf, ref300, dsamp_bf, kNQ);
    hipLaunchKernelGGL((gemm_ln_k<0, 1>), dim3(grid_lnd), dim3(256), 0, stream,
                       dsamp_bf, dopW + (size_t)i * 65536, dop_b + i * kC,
                       tgt_bf, dn1_g + i * kC, dn1_b + i * kC,
                       tgt, tgt_bf, (unsigned short*)nullptr,
                       (const unsigned short*)nullptr, MD, 256);
    hipLaunchKernelGGL((gemm_mfma_s<1, 1, 0>), dim3(1024 / 64, (MD + 63) / 64), dim3(256), 0,
                       stream, tgt_bf, dl1W + (size_t)i * 262144, dl1_b + i * kFF,
                       dffnh_bf, MD, 1024, 256, (const float*)nullptr, 0);
    hipLaunchKernelGGL((gemm_ln_k<0, 1>), dim3(grid_lnd), dim3(256), 0, stream,
                       dffnh_bf, dl2W + (size_t)i * 262144, dl2_b + i * kC,
                       tgt_bf, dn3_g + i * kC, dn3_b + i * kC,
                       tgt, tgt_bf, (unsigned short*)nullptr,
                       (const unsigned short*)nullptr, MD, 1024);
  }

  hipMemcpyAsync(d_out, tgt, NQC * sizeof(float), hipMemcpyDeviceToDevice, stream);
  hipLaunchKernelGGL(write_refs_k, dim3(5), dim3(256), 0, stream, ref300, (float*)d_out);
}